// Round 10
// baseline (511.956 us; speedup 1.0000x reference)
//
#include <hip/hip_runtime.h>
#include <hip/hip_bf16.h>

// Round 10: MFMA conv via weights-as-Toeplitz-band.
//  Per (oc,ic,ky): A[m=x][k=ix] = w[ix-m] (banded 16x32, built in regs via
//  v_perm from a prepacked bf16 table); B[k=ix][n=y] = in[y+ky][x0+ix]
//  (one contiguous ds_read_b128 per lane). C[x][y] accumulates 15 MFMAs
//  (3 ic x 5 ky) -> one 16x16 output tile per oc.
//  Layouts (gfx950 16x16x32 bf16): A: m=lane%16, k=(lane>>4)*8+j;
//  B: n=lane%16, same k; C: n=lane&15, m=(lane>>4)*4+reg  [learn_hip m89].
//  Block: 256 thr = 4 waves; tile 64x32; wave sx=wid, sub-tiles sy=0,1;
//  4 images per block (img loop, re-staged each).
//  conv3 fuses pooling: sub-tile == one 16x16 patch -> wave butterfly sum.

#define CT 256

typedef unsigned int u32;
typedef short bf16x8 __attribute__((ext_vector_type(8)));
typedef float f32x4 __attribute__((ext_vector_type(4)));
typedef unsigned int u32x4 __attribute__((ext_vector_type(4)));

static __device__ __forceinline__ unsigned short f2bf(float f) {
    __hip_bfloat16 h = __float2bfloat16(f);
    return *reinterpret_cast<unsigned short*>(&h);
}

// ---- LDS geometry: ushort sIn[3][36][88]; row stride 88 (176 B, 16B mult,
//      2-way banks); channel 3168 elems (6336 B). Cols 0..79 hold the
//      gx0-2..gx0+77 window (zero-masked OOB), 80..87 zero pad. ----
#define LSTRIDE 88
#define LCH     3168

// ---------------- weight pack prologue ----------------
// tab[t*3+{0,1,2}] = {bf16(w0)|bf16(w1)<<16, bf16(w2)|bf16(w3)<<16, bf16(w4)}
// t: conv1 rows 0..44, conv2 45..89, conv3 90..104 (row = (oc*3+ic)*5+ky).
__global__ __launch_bounds__(128) void pack_weights(
    const float* __restrict__ w1, const float* __restrict__ w2,
    const float* __restrict__ w3, u32* __restrict__ tab)
{
    const int t = threadIdx.x;
    if (t < 105) {
        const float* w;
        if (t < 45)       w = w1 + t * 5;
        else if (t < 90)  w = w2 + (t - 45) * 5;
        else              w = w3 + (t - 90) * 5;
        tab[t * 3 + 0] = (u32)f2bf(w[0]) | ((u32)f2bf(w[1]) << 16);
        tab[t * 3 + 1] = (u32)f2bf(w[2]) | ((u32)f2bf(w[3]) << 16);
        tab[t * 3 + 2] = (u32)f2bf(w[4]);
    }
}

// ---------------- MFMA conv stage ----------------
template<bool IN_F32, int OC, bool POOL, int TABOFF>
__global__ __launch_bounds__(CT) void conv_mfma(
    const void* __restrict__ in_, const float* __restrict__ bias,
    const u32* __restrict__ tab,
    unsigned short* __restrict__ out_, float* __restrict__ feat)
{
    const int pos = blockIdx.x;            // 0..31
    const int grp = blockIdx.y;            // 0..63 (4 images each)
    const int tx  = pos & 3, ty = pos >> 2;
    const int tid = threadIdx.x;
    const int lane = tid & 63, wid = tid >> 6;
    const int lanem = lane & 15, g = lane >> 4;

    __shared__ __align__(16) unsigned short sIn[3 * LCH];   // 19008 B

    const int gy0 = ty * 32, gx0 = tx * 64;

    // ---- per-lane perm selectors for the Toeplitz A build (once) ----
    u32 selA[4], selB[4];
#pragma unroll
    for (int jj = 0; jj < 4; ++jj) {
        u32 a = 0, bs = 0;
#pragma unroll
        for (int byt = 0; byt < 4; ++byt) {
            const int j = 2 * jj + (byt >> 1);
            const int d = g * 8 + j - lanem;       // w index for A[m][k]
            const int h = byt & 1;
            u32 av, bv;
            if      (d == 0) av = 0 + h;           // w01 bytes 0/1
            else if (d == 1) av = 2 + h;           // w01 bytes 2/3
            else if (d == 2) av = 4 + h;           // w23 bytes 0/1
            else if (d == 3) av = 6 + h;           // w23 bytes 2/3
            else             av = 0;               // don't care
            if      (d == 4)           bv = 0 + h; // w4z bytes 0/1 (= w4)
            else if (d >= 0 && d < 4)  bv = 4 + byt; // keep t's own byte
            else                       bv = 2 + h; // w4z bytes 2/3 (= 0)
            a  |= av << (8 * byt);
            bs |= bv << (8 * byt);
        }
        selA[jj] = a; selB[jj] = bs;
    }

    // ---- per-lane B read base (byte offset into sIn) ----
    const int bbase = (lanem * LSTRIDE + wid * 16 + g * 8) * 2;

    for (int i = 0; i < 4; ++i) {
        const int b = grp * 4 + i;

        // ---- stage 36 rows x 88 cols x 3 ch as bf16 (zero-padded) ----
        for (int p = tid; p < 36 * 44; p += CT) {
            const int r  = p / 44;
            const int k  = p - r * 44;
            const int gy = gy0 - 2 + r;
            const int gx = gx0 - 2 + 2 * k;
            const bool yok  = (unsigned)gy < 256u;
            const bool full = yok & (gx >= 0) & (gx + 1 < 256);
#pragma unroll
            for (int c = 0; c < 3; ++c) {
                u32 packed = 0;
                if (IN_F32) {
                    const float* src = (const float*)in_ +
                        (((size_t)b * 3 + c) * 256 + gy) * 256;
                    float vx = 0.f, vy = 0.f;
                    if (full) {
                        const float2 v = *reinterpret_cast<const float2*>(src + gx);
                        vx = v.x; vy = v.y;
                    } else if (yok) {
                        if ((unsigned)gx < 256u)       vx = src[gx];
                        if ((unsigned)(gx + 1) < 256u) vy = src[gx + 1];
                    }
                    packed = (u32)f2bf(vx) | ((u32)f2bf(vy) << 16);
                } else {
                    const unsigned short* src = (const unsigned short*)in_ +
                        (((size_t)b * 3 + c) * 256 + gy) * 256;
                    if (full) {
                        packed = *reinterpret_cast<const u32*>(src + gx);
                    } else if (yok) {
                        u32 lo = 0, hi = 0;
                        if ((unsigned)gx < 256u)       lo = src[gx];
                        if ((unsigned)(gx + 1) < 256u) hi = src[gx + 1];
                        packed = lo | (hi << 16);
                    }
                }
                *reinterpret_cast<u32*>(&sIn[c * LCH + r * LSTRIDE + 2 * k]) = packed;
            }
        }
        __syncthreads();

        // ---- compute: per oc build A (15 frags) then 2 sub-tiles x 15 MFMA ----
#pragma unroll
        for (int oc = 0; oc < OC; ++oc) {
            bf16x8 A[15];
#pragma unroll
            for (int ic = 0; ic < 3; ++ic)
#pragma unroll
            for (int ky = 0; ky < 5; ++ky) {
                const u32* wt = tab + (TABOFF + ((oc * 3 + ic) * 5 + ky) * 3);
                const u32 w01 = wt[0], w23 = wt[1], w4z = wt[2];
                u32x4 q;
#pragma unroll
                for (int jj = 0; jj < 4; ++jj) {
                    const u32 t1 = __builtin_amdgcn_perm(w23, w01, selA[jj]);
                    q[jj] = __builtin_amdgcn_perm(t1, w4z, selB[jj]);
                }
                A[ic * 5 + ky] = __builtin_bit_cast(bf16x8, q);
            }

            const float bb = bias[oc];
#pragma unroll
            for (int sy = 0; sy < 2; ++sy) {
                f32x4 acc = {bb, bb, bb, bb};
#pragma unroll
                for (int ic = 0; ic < 3; ++ic)
#pragma unroll
                for (int ky = 0; ky < 5; ++ky) {
                    const bf16x8 Bf = *reinterpret_cast<const bf16x8*>(
                        (const char*)sIn + bbase + sy * (16 * LSTRIDE * 2)
                        + ic * (LCH * 2) + ky * (LSTRIDE * 2));
                    acc = __builtin_amdgcn_mfma_f32_16x16x32_bf16(
                        A[ic * 5 + ky], Bf, acc, 0, 0, 0);
                }

                if (!POOL) {
                    // lane: y = lanem, x = g*4 + r (4 consecutive)
                    const int Y  = gy0 + sy * 16 + lanem;
                    const int Xb = gx0 + wid * 16 + g * 4;
                    const u32 lo = (u32)f2bf(fmaxf(acc[0], 0.f)) |
                                   ((u32)f2bf(fmaxf(acc[1], 0.f)) << 16);
                    const u32 hi = (u32)f2bf(fmaxf(acc[2], 0.f)) |
                                   ((u32)f2bf(fmaxf(acc[3], 0.f)) << 16);
                    unsigned short* dst = out_ +
                        (((size_t)b * OC + oc) * 256 + Y) * 256 + Xb;
                    *reinterpret_cast<uint2*>(dst) = make_uint2(lo, hi);
                } else {
                    // sub-tile == one 16x16 patch: j = ty*2+sy, i2 = tx*4+wid
                    float s = fmaxf(acc[0], 0.f) + fmaxf(acc[1], 0.f)
                            + fmaxf(acc[2], 0.f) + fmaxf(acc[3], 0.f);
                    s += __shfl_xor(s, 1, 64);
                    s += __shfl_xor(s, 2, 64);
                    s += __shfl_xor(s, 4, 64);
                    s += __shfl_xor(s, 8, 64);
                    s += __shfl_xor(s, 16, 64);
                    s += __shfl_xor(s, 32, 64);
                    if (lane == 0) {
                        const int j = ty * 2 + sy, i2 = tx * 4 + wid;
                        feat[(size_t)b * 256 + j * 16 + i2] = s * (1.f / 256.f);
                    }
                }
            }
        }
        __syncthreads();
    }
}

// ---------------- fused fallback (round-3 kernel) ----------------
#define NTHREADS 512

template<int ICn, int OCn, int OW, int OH, int IS, int ICSZ, int OS, int OCSZ, bool MASK>
__device__ __forceinline__ void conv5x5(
    const float* __restrict__ sin, float* __restrict__ sout,
    const float* __restrict__ w, const float* __restrict__ bias,
    int gy0, int gx0, int tid)
{
    constexpr int QX = OW / 4;
    constexpr int RY = OH / 2;
    constexpr int TASKS = QX * RY;
    if (tid < TASKS) {
        const int ry = tid / QX;
        const int qx = tid - ry * QX;
        const int y0 = ry * 2, x0 = qx * 4;
        float acc[2][OCn][4];
#pragma unroll
        for (int c = 0; c < OCn; ++c) {
            const float bb = bias[c];
#pragma unroll
            for (int p = 0; p < 4; ++p) { acc[0][c][p] = bb; acc[1][c][p] = bb; }
        }
#pragma unroll
        for (int ic = 0; ic < ICn; ++ic) {
            const float* base = sin + ic * ICSZ + y0 * IS + x0;
#pragma unroll
            for (int r = 0; r < 6; ++r) {
                const float4 a4 = *reinterpret_cast<const float4*>(base + r * IS);
                const float4 b4 = *reinterpret_cast<const float4*>(base + r * IS + 4);
                const float v[8] = {a4.x, a4.y, a4.z, a4.w, b4.x, b4.y, b4.z, b4.w};
#pragma unroll
                for (int kx = 0; kx < 5; ++kx)
#pragma unroll
                    for (int c = 0; c < OCn; ++c) {
                        if (r < 5) {
                            const float wv = w[((c * ICn + ic) * 5 + r) * 5 + kx];
#pragma unroll
                            for (int p = 0; p < 4; ++p)
                                acc[0][c][p] = fmaf(v[p + kx], wv, acc[0][c][p]);
                        }
                        if (r >= 1) {
                            const float wv = w[((c * ICn + ic) * 5 + (r - 1)) * 5 + kx];
#pragma unroll
                            for (int p = 0; p < 4; ++p)
                                acc[1][c][p] = fmaf(v[p + kx], wv, acc[1][c][p]);
                        }
                    }
            }
        }
#pragma unroll
        for (int rr = 0; rr < 2; ++rr) {
            const int gy = gy0 + y0 + rr;
#pragma unroll
            for (int c = 0; c < OCn; ++c) {
                float o[4];
#pragma unroll
                for (int p = 0; p < 4; ++p) {
                    float rv = fmaxf(acc[rr][c][p], 0.f);
                    if (MASK) {
                        const int gx = gx0 + x0 + p;
                        const bool ok = ((unsigned)gy < 256u) & ((unsigned)gx < 256u);
                        rv = ok ? rv : 0.f;
                    }
                    o[p] = rv;
                }
                *reinterpret_cast<float4*>(&sout[c * OCSZ + (y0 + rr) * OS + x0]) =
                    make_float4(o[0], o[1], o[2], o[3]);
            }
        }
    }
}

__global__ __launch_bounds__(NTHREADS) void fused_conv_feat(
    const float* __restrict__ x,
    const float* __restrict__ w1, const float* __restrict__ b1,
    const float* __restrict__ w2, const float* __restrict__ b2,
    const float* __restrict__ w3, const float* __restrict__ b3,
    float* __restrict__ feat)
{
    const int tile = blockIdx.x;
    const int b    = blockIdx.y;
    const int tx   = tile & 3, ty = tile >> 2;
    const int tid  = threadIdx.x;

    __shared__ __align__(16) float lds[10032 + 9120];
    float* sIn = lds;
    float* sH1 = lds + 10032;
    float* sH2 = lds;
    float* sH3 = lds + 10032;

    const int gy0s = ty * 32 - 6, gx0s = tx * 64 - 6;
    for (int i = tid; i < 3 * 44 * 38; i += NTHREADS) {
        const int c   = i / 1672;
        const int rem = i - c * 1672;
        const int r   = rem / 38;
        const int k   = rem - r * 38;
        const int gy = gy0s + r, gx = gx0s + 2 * k;
        float2 v = make_float2(0.f, 0.f);
        if ((unsigned)gy < 256u) {
            const float* src = x + (((size_t)b * 3 + c) * 256 + gy) * 256;
            if (gx >= 0 && gx + 1 < 256) {
                v = *reinterpret_cast<const float2*>(src + gx);
            } else {
                if ((unsigned)gx < 256u)       v.x = src[gx];
                if ((unsigned)(gx + 1) < 256u) v.y = src[gx + 1];
            }
        }
        *reinterpret_cast<float2*>(&sIn[c * 3344 + r * 76 + 2 * k]) = v;
    }
    __syncthreads();

    conv5x5<3, 3, 72, 40, 76, 3344, 76, 3040, true>(sIn, sH1, w1, b1,
                                                    ty * 32 - 4, tx * 64 - 4, tid);
    __syncthreads();
    conv5x5<3, 3, 68, 36, 76, 3040, 76, 2736, true>(sH1, sH2, w2, b2,
                                                    ty * 32 - 2, tx * 64 - 2, tid);
    __syncthreads();
    conv5x5<3, 1, 64, 32, 76, 2736, 64, 2048, false>(sH2, sH3, w3, b3, 0, 0, tid);
    __syncthreads();

    const int wv   = tid >> 6;
    const int lane = tid & 63;
    const int py = wv >> 2, px = wv & 3;
    float s = 0.f;
#pragma unroll
    for (int k = 0; k < 4; ++k) {
        const int idx = lane + k * 64;
        const int r = idx >> 4, cc = idx & 15;
        s += sH3[(py * 16 + r) * 64 + px * 16 + cc];
    }
#pragma unroll
    for (int off = 32; off > 0; off >>= 1) s += __shfl_down(s, off, 64);
    if (lane == 0) {
        const int j = ty * 2 + py, i = tx * 4 + px;
        feat[(size_t)b * 256 + j * 16 + i] = s * (1.f / 256.f);
    }
}

// ---------------- MLP head ----------------
__global__ __launch_bounds__(64) void mlp_head(
    const float* __restrict__ feat,
    const float* __restrict__ wl1, const float* __restrict__ bl1,
    const float* __restrict__ wl2, const float* __restrict__ bl2,
    float* __restrict__ out)
{
    const int b = blockIdx.x;
    const int t = threadIdx.x;

    __shared__ float sF[256];
    __shared__ float sE[64];
    __shared__ float sL[8];
    __shared__ float sX[8];

    for (int i = t; i < 256; i += 64) sF[i] = feat[(size_t)b * 256 + i];
    __syncthreads();

    float acc = bl1[t];
    for (int k = 0; k < 256; ++k) acc = fmaf(sF[k], wl1[t * 256 + k], acc);
    sE[t] = acc;
    __syncthreads();

    if (t < 8) {
        float l = bl2[t];
#pragma unroll
        for (int k = 0; k < 64; ++k) l = fmaf(sE[k], wl2[t * 64 + k], l);
        sL[t] = l;
    }
    __syncthreads();

    if (t < 8) {
        float m = sL[0];
#pragma unroll
        for (int k = 1; k < 8; ++k) m = fmaxf(m, sL[k]);
        sX[t] = __expf(sL[t] - m);
    }
    __syncthreads();

    if (t < 8) {
        float sum = 0.f;
#pragma unroll
        for (int k = 0; k < 8; ++k) sum += sX[k];
        out[(size_t)b * 8 + t] = sX[t] / sum;
    }
}

extern "C" void kernel_launch(void* const* d_in, const int* in_sizes, int n_in,
                              void* d_out, int out_size, void* d_ws, size_t ws_size,
                              hipStream_t stream) {
    const float* x   = (const float*)d_in[0];
    const float* w1  = (const float*)d_in[1];
    const float* b1  = (const float*)d_in[2];
    const float* w2  = (const float*)d_in[3];
    const float* b2  = (const float*)d_in[4];
    const float* w3  = (const float*)d_in[5];
    const float* b3  = (const float*)d_in[6];
    const float* wl1 = (const float*)d_in[7];
    const float* bl1 = (const float*)d_in[8];
    const float* wl2 = (const float*)d_in[9];
    const float* bl2 = (const float*)d_in[10];
    float* out  = (float*)d_out;

    const size_t FEAT_B = 256u * 256u * 4u;                 // 262144
    const size_t H_B    = (size_t)256 * 3 * 256 * 256 * 2;  // 100663296
    const size_t TAB_B  = 4096;
    float* feat = (float*)d_ws;

    if (ws_size >= FEAT_B + 2 * H_B + TAB_B) {
        unsigned short* h1 = (unsigned short*)((char*)d_ws + FEAT_B);
        unsigned short* h2 = (unsigned short*)((char*)d_ws + FEAT_B + H_B);
        u32* wtab = (u32*)((char*)d_ws + FEAT_B + 2 * H_B);

        pack_weights<<<1, 128, 0, stream>>>(w1, w2, w3, wtab);
        dim3 g(32, 64);
        conv_mfma<true,  3, false, 0  ><<<g, CT, 0, stream>>>(x,  b1, wtab, h1, nullptr);
        conv_mfma<false, 3, false, 135><<<g, CT, 0, stream>>>(h1, b2, wtab, h2, nullptr);
        conv_mfma<false, 1, true,  270><<<g, CT, 0, stream>>>(h2, b3, wtab, nullptr, feat);
    } else {
        dim3 g1(32, 256);
        fused_conv_feat<<<g1, NTHREADS, 0, stream>>>(x, w1, b1, w2, b2, w3, b3, feat);
    }
    mlp_head<<<256, 64, 0, stream>>>(feat, wl1, bl1, wl2, bl2, out);
}

// Round 11
// 378.469 us; speedup vs baseline: 1.3527x; 1.3527x over previous
//
#include <hip/hip_runtime.h>
#include <hip/hip_bf16.h>

// Round 11: MFMA Toeplitz conv, restructured for ILP.
//  - A-fragments (per-lane, weight-only) precomputed ONCE into a global
//    table by pack_afrags (105 frags x 64 lanes x 16 B = 107 KB, L2-hot);
//    conv kernel loads them with coalesced global_load_dwordx4.
//  - Loop (ic,ky) outer, {oc x sy} inner: per iter 2 ds_read_b128 (B for
//    sy=0,1, shared across oc) + 6 independent MFMAs -> dep distance ~29cyc.
//  - One image per block (grid 32 x 256), single barrier.
//  Math identical to round 10 (passed, absmax 4.9e-4): same frag layouts,
//  same per-acc summation order.

#define CT 256

typedef unsigned int u32;
typedef short bf16x8 __attribute__((ext_vector_type(8)));
typedef float f32x4 __attribute__((ext_vector_type(4)));
typedef unsigned int u32x4 __attribute__((ext_vector_type(4)));

static __device__ __forceinline__ unsigned short f2bf(float f) {
    __hip_bfloat16 h = __float2bfloat16(f);
    return *reinterpret_cast<unsigned short*>(&h);
}

#define LSTRIDE 88
#define LCH     3168

// ---------------- A-fragment precompute ----------------
// Row t = 0..104: conv1 rows 0..44 ((oc*3+ic)*5+ky), conv2 45..89, conv3 90..104.
// A_tab[(t*64+lane)*4 + jj] = per-lane Toeplitz fragment word jj.
__global__ __launch_bounds__(CT) void pack_afrags(
    const float* __restrict__ w1, const float* __restrict__ w2,
    const float* __restrict__ w3, u32* __restrict__ A_tab)
{
    const int idx = blockIdx.x * CT + threadIdx.x;
    if (idx >= 105 * 64) return;
    const int t = idx >> 6, lane = idx & 63;
    const int lanem = lane & 15, g = lane >> 4;

    const float* w;
    if (t < 45)       w = w1 + t * 5;
    else if (t < 90)  w = w2 + (t - 45) * 5;
    else              w = w3 + (t - 90) * 5;

    const u32 w01 = (u32)f2bf(w[0]) | ((u32)f2bf(w[1]) << 16);
    const u32 w23 = (u32)f2bf(w[2]) | ((u32)f2bf(w[3]) << 16);
    const u32 w4z = (u32)f2bf(w[4]);

#pragma unroll
    for (int jj = 0; jj < 4; ++jj) {
        u32 a = 0, bs = 0;
#pragma unroll
        for (int byt = 0; byt < 4; ++byt) {
            const int j = 2 * jj + (byt >> 1);
            const int d = g * 8 + j - lanem;       // w index for A[m][k]
            const int h = byt & 1;
            u32 av, bv;
            if      (d == 0) av = 0 + h;
            else if (d == 1) av = 2 + h;
            else if (d == 2) av = 4 + h;
            else if (d == 3) av = 6 + h;
            else             av = 0;
            if      (d == 4)           bv = 0 + h;   // w4
            else if (d >= 0 && d < 4)  bv = 4 + byt; // keep t1 byte
            else                       bv = 2 + h;   // zero (w4z hi half)
            a  |= av << (8 * byt);
            bs |= bv << (8 * byt);
        }
        const u32 t1 = __builtin_amdgcn_perm(w23, w01, a);
        A_tab[idx * 4 + jj] = __builtin_amdgcn_perm(t1, w4z, bs);
    }
}

// ---------------- MFMA conv stage ----------------
template<bool IN_F32, int OC, bool POOL, int TABOFF>
__global__ __launch_bounds__(CT) void conv_mfma(
    const void* __restrict__ in_, const float* __restrict__ bias,
    const u32* __restrict__ A_tab,
    unsigned short* __restrict__ out_, float* __restrict__ feat)
{
    const int pos = blockIdx.x;            // 0..31
    const int b   = blockIdx.y;            // image
    const int tx  = pos & 3, ty = pos >> 2;
    const int tid = threadIdx.x;
    const int lane = tid & 63, wid = tid >> 6;
    const int lanem = lane & 15, g = lane >> 4;

    __shared__ __align__(16) unsigned short sIn[3 * LCH];   // 19008 B

    const int gy0 = ty * 32, gx0 = tx * 64;

    // ---- stage 36 rows x 88 cols x 3 ch as bf16 (zero-padded) ----
    for (int p = tid; p < 36 * 44; p += CT) {
        const int r  = p / 44;
        const int k  = p - r * 44;
        const int gy = gy0 - 2 + r;
        const int gx = gx0 - 2 + 2 * k;
        const bool yok  = (unsigned)gy < 256u;
        const bool full = yok & (gx >= 0) & (gx + 1 < 256);
#pragma unroll
        for (int c = 0; c < 3; ++c) {
            u32 packed = 0;
            if (IN_F32) {
                const float* src = (const float*)in_ +
                    (((size_t)b * 3 + c) * 256 + gy) * 256;
                float vx = 0.f, vy = 0.f;
                if (full) {
                    const float2 v = *reinterpret_cast<const float2*>(src + gx);
                    vx = v.x; vy = v.y;
                } else if (yok) {
                    if ((unsigned)gx < 256u)       vx = src[gx];
                    if ((unsigned)(gx + 1) < 256u) vy = src[gx + 1];
                }
                packed = (u32)f2bf(vx) | ((u32)f2bf(vy) << 16);
            } else {
                const unsigned short* src = (const unsigned short*)in_ +
                    (((size_t)b * 3 + c) * 256 + gy) * 256;
                if (full) {
                    packed = *reinterpret_cast<const u32*>(src + gx);
                } else if (yok) {
                    u32 lo = 0, hi = 0;
                    if ((unsigned)gx < 256u)       lo = src[gx];
                    if ((unsigned)(gx + 1) < 256u) hi = src[gx + 1];
                    packed = lo | (hi << 16);
                }
            }
            *reinterpret_cast<u32*>(&sIn[c * LCH + r * LSTRIDE + 2 * k]) = packed;
        }
    }
    __syncthreads();

    // ---- compute: (ic,ky) outer, {oc x sy} inner (6-way MFMA ILP) ----
    const int bbase = (lanem * LSTRIDE + wid * 16 + g * 8) * 2;
    const u32* atb = A_tab + (size_t)(TABOFF * 64 + lane) * 4;

    f32x4 acc[OC][2];
#pragma unroll
    for (int oc = 0; oc < OC; ++oc) {
        const float bb = bias[oc];
        acc[oc][0] = f32x4{bb, bb, bb, bb};
        acc[oc][1] = f32x4{bb, bb, bb, bb};
    }

#pragma unroll
    for (int f = 0; f < 15; ++f) {         // f = ic*5 + ky
        const int ic = f / 5, ky = f % 5;
        const char* bp = (const char*)sIn + bbase
                       + ic * (LCH * 2) + ky * (LSTRIDE * 2);
        const bf16x8 B0 = *reinterpret_cast<const bf16x8*>(bp);
        const bf16x8 B1 = *reinterpret_cast<const bf16x8*>(bp + 16 * LSTRIDE * 2);
#pragma unroll
        for (int oc = 0; oc < OC; ++oc) {
            const u32x4 q = *reinterpret_cast<const u32x4*>(
                atb + (size_t)((oc * 3 + ic) * 5 + ky) * 64 * 4);
            const bf16x8 A = __builtin_bit_cast(bf16x8, q);
            acc[oc][0] = __builtin_amdgcn_mfma_f32_16x16x32_bf16(A, B0, acc[oc][0], 0, 0, 0);
            acc[oc][1] = __builtin_amdgcn_mfma_f32_16x16x32_bf16(A, B1, acc[oc][1], 0, 0, 0);
        }
    }

    // ---- epilogue ----
#pragma unroll
    for (int oc = 0; oc < OC; ++oc) {
#pragma unroll
        for (int sy = 0; sy < 2; ++sy) {
            const f32x4 a = acc[oc][sy];
            if (!POOL) {
                const int Y  = gy0 + sy * 16 + lanem;
                const int Xb = gx0 + wid * 16 + g * 4;
                const u32 lo = (u32)f2bf(fmaxf(a[0], 0.f)) |
                               ((u32)f2bf(fmaxf(a[1], 0.f)) << 16);
                const u32 hi = (u32)f2bf(fmaxf(a[2], 0.f)) |
                               ((u32)f2bf(fmaxf(a[3], 0.f)) << 16);
                unsigned short* dst = out_ +
                    (((size_t)b * OC + oc) * 256 + Y) * 256 + Xb;
                *reinterpret_cast<uint2*>(dst) = make_uint2(lo, hi);
            } else {
                float s = fmaxf(a[0], 0.f) + fmaxf(a[1], 0.f)
                        + fmaxf(a[2], 0.f) + fmaxf(a[3], 0.f);
                s += __shfl_xor(s, 1, 64);
                s += __shfl_xor(s, 2, 64);
                s += __shfl_xor(s, 4, 64);
                s += __shfl_xor(s, 8, 64);
                s += __shfl_xor(s, 16, 64);
                s += __shfl_xor(s, 32, 64);
                if (lane == 0) {
                    const int j = ty * 2 + sy, i2 = tx * 4 + wid;
                    feat[(size_t)b * 256 + j * 16 + i2] = s * (1.f / 256.f);
                }
            }
        }
    }
}

// ---------------- fused fallback (round-3 kernel) ----------------
#define NTHREADS 512

template<int ICn, int OCn, int OW, int OH, int IS, int ICSZ, int OS, int OCSZ, bool MASK>
__device__ __forceinline__ void conv5x5(
    const float* __restrict__ sin, float* __restrict__ sout,
    const float* __restrict__ w, const float* __restrict__ bias,
    int gy0, int gx0, int tid)
{
    constexpr int QX = OW / 4;
    constexpr int RY = OH / 2;
    constexpr int TASKS = QX * RY;
    if (tid < TASKS) {
        const int ry = tid / QX;
        const int qx = tid - ry * QX;
        const int y0 = ry * 2, x0 = qx * 4;
        float acc[2][OCn][4];
#pragma unroll
        for (int c = 0; c < OCn; ++c) {
            const float bb = bias[c];
#pragma unroll
            for (int p = 0; p < 4; ++p) { acc[0][c][p] = bb; acc[1][c][p] = bb; }
        }
#pragma unroll
        for (int ic = 0; ic < ICn; ++ic) {
            const float* base = sin + ic * ICSZ + y0 * IS + x0;
#pragma unroll
            for (int r = 0; r < 6; ++r) {
                const float4 a4 = *reinterpret_cast<const float4*>(base + r * IS);
                const float4 b4 = *reinterpret_cast<const float4*>(base + r * IS + 4);
                const float v[8] = {a4.x, a4.y, a4.z, a4.w, b4.x, b4.y, b4.z, b4.w};
#pragma unroll
                for (int kx = 0; kx < 5; ++kx)
#pragma unroll
                    for (int c = 0; c < OCn; ++c) {
                        if (r < 5) {
                            const float wv = w[((c * ICn + ic) * 5 + r) * 5 + kx];
#pragma unroll
                            for (int p = 0; p < 4; ++p)
                                acc[0][c][p] = fmaf(v[p + kx], wv, acc[0][c][p]);
                        }
                        if (r >= 1) {
                            const float wv = w[((c * ICn + ic) * 5 + (r - 1)) * 5 + kx];
#pragma unroll
                            for (int p = 0; p < 4; ++p)
                                acc[1][c][p] = fmaf(v[p + kx], wv, acc[1][c][p]);
                        }
                    }
            }
        }
#pragma unroll
        for (int rr = 0; rr < 2; ++rr) {
            const int gy = gy0 + y0 + rr;
#pragma unroll
            for (int c = 0; c < OCn; ++c) {
                float o[4];
#pragma unroll
                for (int p = 0; p < 4; ++p) {
                    float rv = fmaxf(acc[rr][c][p], 0.f);
                    if (MASK) {
                        const int gx = gx0 + x0 + p;
                        const bool ok = ((unsigned)gy < 256u) & ((unsigned)gx < 256u);
                        rv = ok ? rv : 0.f;
                    }
                    o[p] = rv;
                }
                *reinterpret_cast<float4*>(&sout[c * OCSZ + (y0 + rr) * OS + x0]) =
                    make_float4(o[0], o[1], o[2], o[3]);
            }
        }
    }
}

__global__ __launch_bounds__(NTHREADS) void fused_conv_feat(
    const float* __restrict__ x,
    const float* __restrict__ w1, const float* __restrict__ b1,
    const float* __restrict__ w2, const float* __restrict__ b2,
    const float* __restrict__ w3, const float* __restrict__ b3,
    float* __restrict__ feat)
{
    const int tile = blockIdx.x;
    const int b    = blockIdx.y;
    const int tx   = tile & 3, ty = tile >> 2;
    const int tid  = threadIdx.x;

    __shared__ __align__(16) float lds[10032 + 9120];
    float* sIn = lds;
    float* sH1 = lds + 10032;
    float* sH2 = lds;
    float* sH3 = lds + 10032;

    const int gy0s = ty * 32 - 6, gx0s = tx * 64 - 6;
    for (int i = tid; i < 3 * 44 * 38; i += NTHREADS) {
        const int c   = i / 1672;
        const int rem = i - c * 1672;
        const int r   = rem / 38;
        const int k   = rem - r * 38;
        const int gy = gy0s + r, gx = gx0s + 2 * k;
        float2 v = make_float2(0.f, 0.f);
        if ((unsigned)gy < 256u) {
            const float* src = x + (((size_t)b * 3 + c) * 256 + gy) * 256;
            if (gx >= 0 && gx + 1 < 256) {
                v = *reinterpret_cast<const float2*>(src + gx);
            } else {
                if ((unsigned)gx < 256u)       v.x = src[gx];
                if ((unsigned)(gx + 1) < 256u) v.y = src[gx + 1];
            }
        }
        *reinterpret_cast<float2*>(&sIn[c * 3344 + r * 76 + 2 * k]) = v;
    }
    __syncthreads();

    conv5x5<3, 3, 72, 40, 76, 3344, 76, 3040, true>(sIn, sH1, w1, b1,
                                                    ty * 32 - 4, tx * 64 - 4, tid);
    __syncthreads();
    conv5x5<3, 3, 68, 36, 76, 3040, 76, 2736, true>(sH1, sH2, w2, b2,
                                                    ty * 32 - 2, tx * 64 - 2, tid);
    __syncthreads();
    conv5x5<3, 1, 64, 32, 76, 2736, 64, 2048, false>(sH2, sH3, w3, b3, 0, 0, tid);
    __syncthreads();

    const int wv   = tid >> 6;
    const int lane = tid & 63;
    const int py = wv >> 2, px = wv & 3;
    float s = 0.f;
#pragma unroll
    for (int k = 0; k < 4; ++k) {
        const int idx = lane + k * 64;
        const int r = idx >> 4, cc = idx & 15;
        s += sH3[(py * 16 + r) * 64 + px * 16 + cc];
    }
#pragma unroll
    for (int off = 32; off > 0; off >>= 1) s += __shfl_down(s, off, 64);
    if (lane == 0) {
        const int j = ty * 2 + py, i = tx * 4 + px;
        feat[(size_t)b * 256 + j * 16 + i] = s * (1.f / 256.f);
    }
}

// ---------------- MLP head ----------------
__global__ __launch_bounds__(64) void mlp_head(
    const float* __restrict__ feat,
    const float* __restrict__ wl1, const float* __restrict__ bl1,
    const float* __restrict__ wl2, const float* __restrict__ bl2,
    float* __restrict__ out)
{
    const int b = blockIdx.x;
    const int t = threadIdx.x;

    __shared__ float sF[256];
    __shared__ float sE[64];
    __shared__ float sL[8];
    __shared__ float sX[8];

    for (int i = t; i < 256; i += 64) sF[i] = feat[(size_t)b * 256 + i];
    __syncthreads();

    float acc = bl1[t];
    for (int k = 0; k < 256; ++k) acc = fmaf(sF[k], wl1[t * 256 + k], acc);
    sE[t] = acc;
    __syncthreads();

    if (t < 8) {
        float l = bl2[t];
#pragma unroll
        for (int k = 0; k < 64; ++k) l = fmaf(sE[k], wl2[t * 64 + k], l);
        sL[t] = l;
    }
    __syncthreads();

    if (t < 8) {
        float m = sL[0];
#pragma unroll
        for (int k = 1; k < 8; ++k) m = fmaxf(m, sL[k]);
        sX[t] = __expf(sL[t] - m);
    }
    __syncthreads();

    if (t < 8) {
        float sum = 0.f;
#pragma unroll
        for (int k = 0; k < 8; ++k) sum += sX[k];
        out[(size_t)b * 8 + t] = sX[t] / sum;
    }
}

extern "C" void kernel_launch(void* const* d_in, const int* in_sizes, int n_in,
                              void* d_out, int out_size, void* d_ws, size_t ws_size,
                              hipStream_t stream) {
    const float* x   = (const float*)d_in[0];
    const float* w1  = (const float*)d_in[1];
    const float* b1  = (const float*)d_in[2];
    const float* w2  = (const float*)d_in[3];
    const float* b2  = (const float*)d_in[4];
    const float* w3  = (const float*)d_in[5];
    const float* b3  = (const float*)d_in[6];
    const float* wl1 = (const float*)d_in[7];
    const float* bl1 = (const float*)d_in[8];
    const float* wl2 = (const float*)d_in[9];
    const float* bl2 = (const float*)d_in[10];
    float* out  = (float*)d_out;

    const size_t FEAT_B = 256u * 256u * 4u;                 // 262144
    const size_t H_B    = (size_t)256 * 3 * 256 * 256 * 2;  // 100663296
    const size_t ATAB_B = 105 * 64 * 4 * sizeof(u32);       // 107520
    float* feat = (float*)d_ws;

    if (ws_size >= FEAT_B + 2 * H_B + ATAB_B) {
        unsigned short* h1 = (unsigned short*)((char*)d_ws + FEAT_B);
        unsigned short* h2 = (unsigned short*)((char*)d_ws + FEAT_B + H_B);
        u32* atab = (u32*)((char*)d_ws + FEAT_B + 2 * H_B);

        pack_afrags<<<(105 * 64 + CT - 1) / CT, CT, 0, stream>>>(w1, w2, w3, atab);
        dim3 g(32, 256);
        conv_mfma<true,  3, false, 0 ><<<g, CT, 0, stream>>>(x,  b1, atab, h1, nullptr);
        conv_mfma<false, 3, false, 45><<<g, CT, 0, stream>>>(h1, b2, atab, h2, nullptr);
        conv_mfma<false, 1, true,  90><<<g, CT, 0, stream>>>(h2, b3, atab, nullptr, feat);
    } else {
        dim3 g1(32, 256);
        fused_conv_feat<<<g1, NTHREADS, 0, stream>>>(x, w1, b1, w2, b2, w3, b3, feat);
    }
    mlp_head<<<256, 64, 0, stream>>>(feat, wl1, bl1, wl2, bl2, out);
}

// Round 12
// 324.823 us; speedup vs baseline: 1.5761x; 1.1652x over previous
//
#include <hip/hip_runtime.h>
#include <hip/hip_bf16.h>

// Round 12: MFMA Toeplitz conv, latency-focused restructure.
//  - A-fragments built in-register via v_perm (round-10 verified selectors)
//    from a compact uniform weight table (s_load'ed) -> no per-frag global
//    load latency (round-11's 45 x ~200cyc L2 exposure removed).
//  - 2 images per block (grid 32x128), both staged upfront into separate
//    LDS buffers -> 2x staging MLP, per-block fixed costs halved, each
//    A build amortized over 4 MFMAs (2 img x 2 sy).
//  - LDS stride 72 (stage exactly the needed 72-col window + zeroed pad;
//    reads beyond col 67 multiply the zero Toeplitz band -> pad zeroed to
//    avoid 0 x uninit-NaN).
//  Math identical to rounds 10/11 (passed, absmax 4.9e-4).

#define CT 256

typedef unsigned int u32;
typedef short bf16x8 __attribute__((ext_vector_type(8)));
typedef float f32x4 __attribute__((ext_vector_type(4)));

static __device__ __forceinline__ unsigned short f2bf(float f) {
    __hip_bfloat16 h = __float2bfloat16(f);
    return *reinterpret_cast<unsigned short*>(&h);
}

#define LSTRIDE 72
#define LROWS   36
#define LCH     (LROWS * LSTRIDE)     // 2592 ushorts
#define SBUF    (3 * LCH + 16)        // 7792 ushorts per image (16 = zero pad)

// ---------------- weight pack (compact uniform table) ----------------
// tab[t*3+{0,1,2}] = {bf16(w0)|bf16(w1)<<16, bf16(w2)|bf16(w3)<<16, bf16(w4)}
// t: conv1 rows 0..44 ((oc*3+ic)*5+ky), conv2 45..89, conv3 90..104.
__global__ __launch_bounds__(128) void pack_weights(
    const float* __restrict__ w1, const float* __restrict__ w2,
    const float* __restrict__ w3, u32* __restrict__ tab)
{
    const int t = threadIdx.x;
    if (t < 105) {
        const float* w;
        if (t < 45)       w = w1 + t * 5;
        else if (t < 90)  w = w2 + (t - 45) * 5;
        else              w = w3 + (t - 90) * 5;
        tab[t * 3 + 0] = (u32)f2bf(w[0]) | ((u32)f2bf(w[1]) << 16);
        tab[t * 3 + 1] = (u32)f2bf(w[2]) | ((u32)f2bf(w[3]) << 16);
        tab[t * 3 + 2] = (u32)f2bf(w[4]);
    }
}

// ---------------- MFMA conv stage ----------------
template<bool IN_F32, int OC, bool POOL, int TABOFF>
__global__ __launch_bounds__(CT) void conv_mfma(
    const void* __restrict__ in_, const float* __restrict__ bias,
    const u32* __restrict__ tab,
    unsigned short* __restrict__ out_, float* __restrict__ feat)
{
    const int pos  = blockIdx.x;           // 0..31 spatial tile
    const int pair = blockIdx.y;           // 0..127 image pair
    const int tx = pos & 3, ty = pos >> 2;
    const int tid = threadIdx.x;
    const int lane = tid & 63, wid = tid >> 6;
    const int lanem = lane & 15, g = lane >> 4;

    __shared__ __align__(16) unsigned short sIn[2 * SBUF];   // 31168 B

    const int gy0 = ty * 32, gx0 = tx * 64;

    // ---- per-lane perm selectors (round-10 verified) ----
    u32 selA[4], selB[4];
#pragma unroll
    for (int jj = 0; jj < 4; ++jj) {
        u32 a = 0, bs = 0;
#pragma unroll
        for (int byt = 0; byt < 4; ++byt) {
            const int j = 2 * jj + (byt >> 1);
            const int d = g * 8 + j - lanem;
            const int h = byt & 1;
            u32 av, bv;
            if      (d == 0) av = 0 + h;
            else if (d == 1) av = 2 + h;
            else if (d == 2) av = 4 + h;
            else if (d == 3) av = 6 + h;
            else             av = 0;
            if      (d == 4)           bv = 0 + h;   // w4
            else if (d >= 0 && d < 4)  bv = 4 + byt; // keep t1 byte
            else                       bv = 2 + h;   // zero
            a  |= av << (8 * byt);
            bs |= bv << (8 * byt);
        }
        selA[jj] = a; selB[jj] = bs;
    }

    // ---- zero the per-image LDS tail pads (zero-band reads touch them) ----
    if (tid < 16) {
        const int im = tid >> 3, wpad = tid & 7;
        reinterpret_cast<u32*>(sIn)[((im * SBUF + 3 * LCH) >> 1) + wpad] = 0;
    }

    // ---- stage 2 images: 36 rows x 72 cols x 3 ch, bf16, zero-masked ----
#pragma unroll
    for (int im = 0; im < 2; ++im) {
        const int b = pair * 2 + im;
        for (int p = tid; p < LROWS * 36; p += CT) {
            const int r  = p / 36;
            const int k  = p - r * 36;
            const int gy = gy0 - 2 + r;
            const int gx = gx0 - 2 + 2 * k;
            const bool yok  = (unsigned)gy < 256u;
            const bool full = yok & (gx >= 0) & (gx + 1 < 256);
#pragma unroll
            for (int c = 0; c < 3; ++c) {
                u32 packed = 0;
                if (IN_F32) {
                    const float* src = (const float*)in_ +
                        (((size_t)b * 3 + c) * 256 + gy) * 256;
                    float vx = 0.f, vy = 0.f;
                    if (full) {
                        const float2 v = *reinterpret_cast<const float2*>(src + gx);
                        vx = v.x; vy = v.y;
                    } else if (yok) {
                        if ((unsigned)gx < 256u)       vx = src[gx];
                        if ((unsigned)(gx + 1) < 256u) vy = src[gx + 1];
                    }
                    packed = (u32)f2bf(vx) | ((u32)f2bf(vy) << 16);
                } else {
                    const unsigned short* src = (const unsigned short*)in_ +
                        (((size_t)b * 3 + c) * 256 + gy) * 256;
                    if (full) {
                        packed = *reinterpret_cast<const u32*>(src + gx);
                    } else if (yok) {
                        u32 lo = 0, hi = 0;
                        if ((unsigned)gx < 256u)       lo = src[gx];
                        if ((unsigned)(gx + 1) < 256u) hi = src[gx + 1];
                        packed = lo | (hi << 16);
                    }
                }
                *reinterpret_cast<u32*>(
                    &sIn[im * SBUF + c * LCH + r * LSTRIDE + 2 * k]) = packed;
            }
        }
    }
    __syncthreads();

    // ---- compute: f outer; per f: 4 B ds_reads + 3 A perm-builds + 12 MFMA ----
    const int bbase = (lanem * LSTRIDE + wid * 16 + g * 8) * 2;

    f32x4 acc[OC][2][2];
#pragma unroll
    for (int oc = 0; oc < OC; ++oc) {
        const float bb = bias[oc];
#pragma unroll
        for (int im = 0; im < 2; ++im) {
            acc[oc][im][0] = f32x4{bb, bb, bb, bb};
            acc[oc][im][1] = f32x4{bb, bb, bb, bb};
        }
    }

#pragma unroll
    for (int f = 0; f < 15; ++f) {         // f = ic*5 + ky
        const int ic = f / 5, ky = f % 5;
        bf16x8 Bf[2][2];
#pragma unroll
        for (int im = 0; im < 2; ++im)
#pragma unroll
        for (int sy = 0; sy < 2; ++sy)
            Bf[im][sy] = *reinterpret_cast<const bf16x8*>(
                (const char*)sIn + im * (SBUF * 2) + bbase
                + ic * (LCH * 2) + ky * (LSTRIDE * 2) + sy * (16 * LSTRIDE * 2));

#pragma unroll
        for (int oc = 0; oc < OC; ++oc) {
            const u32* wt = tab + (TABOFF + (oc * 3 + ic) * 5 + ky) * 3;
            const u32 w01 = wt[0], w23 = wt[1], w4z = wt[2];
            u32 q0 = __builtin_amdgcn_perm(__builtin_amdgcn_perm(w23, w01, selA[0]), w4z, selB[0]);
            u32 q1 = __builtin_amdgcn_perm(__builtin_amdgcn_perm(w23, w01, selA[1]), w4z, selB[1]);
            u32 q2 = __builtin_amdgcn_perm(__builtin_amdgcn_perm(w23, w01, selA[2]), w4z, selB[2]);
            u32 q3 = __builtin_amdgcn_perm(__builtin_amdgcn_perm(w23, w01, selA[3]), w4z, selB[3]);
            u32 qq[4] = {q0, q1, q2, q3};
            const bf16x8 A = __builtin_bit_cast(bf16x8, *(reinterpret_cast<unsigned int (*)[4]>(qq)));
#pragma unroll
            for (int im = 0; im < 2; ++im) {
                acc[oc][im][0] = __builtin_amdgcn_mfma_f32_16x16x32_bf16(A, Bf[im][0], acc[oc][im][0], 0, 0, 0);
                acc[oc][im][1] = __builtin_amdgcn_mfma_f32_16x16x32_bf16(A, Bf[im][1], acc[oc][im][1], 0, 0, 0);
            }
        }
    }

    // ---- epilogue ----
#pragma unroll
    for (int oc = 0; oc < OC; ++oc) {
#pragma unroll
        for (int im = 0; im < 2; ++im) {
            const int b = pair * 2 + im;
#pragma unroll
            for (int sy = 0; sy < 2; ++sy) {
                const f32x4 a = acc[oc][im][sy];
                if (!POOL) {
                    const int Y  = gy0 + sy * 16 + lanem;
                    const int Xb = gx0 + wid * 16 + g * 4;
                    const u32 lo = (u32)f2bf(fmaxf(a[0], 0.f)) |
                                   ((u32)f2bf(fmaxf(a[1], 0.f)) << 16);
                    const u32 hi = (u32)f2bf(fmaxf(a[2], 0.f)) |
                                   ((u32)f2bf(fmaxf(a[3], 0.f)) << 16);
                    unsigned short* dst = out_ +
                        (((size_t)b * OC + oc) * 256 + Y) * 256 + Xb;
                    *reinterpret_cast<uint2*>(dst) = make_uint2(lo, hi);
                } else {
                    float s = fmaxf(a[0], 0.f) + fmaxf(a[1], 0.f)
                            + fmaxf(a[2], 0.f) + fmaxf(a[3], 0.f);
                    s += __shfl_xor(s, 1, 64);
                    s += __shfl_xor(s, 2, 64);
                    s += __shfl_xor(s, 4, 64);
                    s += __shfl_xor(s, 8, 64);
                    s += __shfl_xor(s, 16, 64);
                    s += __shfl_xor(s, 32, 64);
                    if (lane == 0) {
                        const int j = ty * 2 + sy, i2 = tx * 4 + wid;
                        feat[(size_t)b * 256 + j * 16 + i2] = s * (1.f / 256.f);
                    }
                }
            }
        }
    }
}

// ---------------- fused fallback (round-3 kernel) ----------------
#define NTHREADS 512

template<int ICn, int OCn, int OW, int OH, int IS, int ICSZ, int OS, int OCSZ, bool MASK>
__device__ __forceinline__ void conv5x5(
    const float* __restrict__ sin, float* __restrict__ sout,
    const float* __restrict__ w, const float* __restrict__ bias,
    int gy0, int gx0, int tid)
{
    constexpr int QX = OW / 4;
    constexpr int RY = OH / 2;
    constexpr int TASKS = QX * RY;
    if (tid < TASKS) {
        const int ry = tid / QX;
        const int qx = tid - ry * QX;
        const int y0 = ry * 2, x0 = qx * 4;
        float acc[2][OCn][4];
#pragma unroll
        for (int c = 0; c < OCn; ++c) {
            const float bb = bias[c];
#pragma unroll
            for (int p = 0; p < 4; ++p) { acc[0][c][p] = bb; acc[1][c][p] = bb; }
        }
#pragma unroll
        for (int ic = 0; ic < ICn; ++ic) {
            const float* base = sin + ic * ICSZ + y0 * IS + x0;
#pragma unroll
            for (int r = 0; r < 6; ++r) {
                const float4 a4 = *reinterpret_cast<const float4*>(base + r * IS);
                const float4 b4 = *reinterpret_cast<const float4*>(base + r * IS + 4);
                const float v[8] = {a4.x, a4.y, a4.z, a4.w, b4.x, b4.y, b4.z, b4.w};
#pragma unroll
                for (int kx = 0; kx < 5; ++kx)
#pragma unroll
                    for (int c = 0; c < OCn; ++c) {
                        if (r < 5) {
                            const float wv = w[((c * ICn + ic) * 5 + r) * 5 + kx];
#pragma unroll
                            for (int p = 0; p < 4; ++p)
                                acc[0][c][p] = fmaf(v[p + kx], wv, acc[0][c][p]);
                        }
                        if (r >= 1) {
                            const float wv = w[((c * ICn + ic) * 5 + (r - 1)) * 5 + kx];
#pragma unroll
                            for (int p = 0; p < 4; ++p)
                                acc[1][c][p] = fmaf(v[p + kx], wv, acc[1][c][p]);
                        }
                    }
            }
        }
#pragma unroll
        for (int rr = 0; rr < 2; ++rr) {
            const int gy = gy0 + y0 + rr;
#pragma unroll
            for (int c = 0; c < OCn; ++c) {
                float o[4];
#pragma unroll
                for (int p = 0; p < 4; ++p) {
                    float rv = fmaxf(acc[rr][c][p], 0.f);
                    if (MASK) {
                        const int gx = gx0 + x0 + p;
                        const bool ok = ((unsigned)gy < 256u) & ((unsigned)gx < 256u);
                        rv = ok ? rv : 0.f;
                    }
                    o[p] = rv;
                }
                *reinterpret_cast<float4*>(&sout[c * OCSZ + (y0 + rr) * OS + x0]) =
                    make_float4(o[0], o[1], o[2], o[3]);
            }
        }
    }
}

__global__ __launch_bounds__(NTHREADS) void fused_conv_feat(
    const float* __restrict__ x,
    const float* __restrict__ w1, const float* __restrict__ b1,
    const float* __restrict__ w2, const float* __restrict__ b2,
    const float* __restrict__ w3, const float* __restrict__ b3,
    float* __restrict__ feat)
{
    const int tile = blockIdx.x;
    const int b    = blockIdx.y;
    const int tx   = tile & 3, ty = tile >> 2;
    const int tid  = threadIdx.x;

    __shared__ __align__(16) float lds[10032 + 9120];
    float* sIn = lds;
    float* sH1 = lds + 10032;
    float* sH2 = lds;
    float* sH3 = lds + 10032;

    const int gy0s = ty * 32 - 6, gx0s = tx * 64 - 6;
    for (int i = tid; i < 3 * 44 * 38; i += NTHREADS) {
        const int c   = i / 1672;
        const int rem = i - c * 1672;
        const int r   = rem / 38;
        const int k   = rem - r * 38;
        const int gy = gy0s + r, gx = gx0s + 2 * k;
        float2 v = make_float2(0.f, 0.f);
        if ((unsigned)gy < 256u) {
            const float* src = x + (((size_t)b * 3 + c) * 256 + gy) * 256;
            if (gx >= 0 && gx + 1 < 256) {
                v = *reinterpret_cast<const float2*>(src + gx);
            } else {
                if ((unsigned)gx < 256u)       v.x = src[gx];
                if ((unsigned)(gx + 1) < 256u) v.y = src[gx + 1];
            }
        }
        *reinterpret_cast<float2*>(&sIn[c * 3344 + r * 76 + 2 * k]) = v;
    }
    __syncthreads();

    conv5x5<3, 3, 72, 40, 76, 3344, 76, 3040, true>(sIn, sH1, w1, b1,
                                                    ty * 32 - 4, tx * 64 - 4, tid);
    __syncthreads();
    conv5x5<3, 3, 68, 36, 76, 3040, 76, 2736, true>(sH1, sH2, w2, b2,
                                                    ty * 32 - 2, tx * 64 - 2, tid);
    __syncthreads();
    conv5x5<3, 1, 64, 32, 76, 2736, 64, 2048, false>(sH2, sH3, w3, b3, 0, 0, tid);
    __syncthreads();

    const int wv   = tid >> 6;
    const int lane = tid & 63;
    const int py = wv >> 2, px = wv & 3;
    float s = 0.f;
#pragma unroll
    for (int k = 0; k < 4; ++k) {
        const int idx = lane + k * 64;
        const int r = idx >> 4, cc = idx & 15;
        s += sH3[(py * 16 + r) * 64 + px * 16 + cc];
    }
#pragma unroll
    for (int off = 32; off > 0; off >>= 1) s += __shfl_down(s, off, 64);
    if (lane == 0) {
        const int j = ty * 2 + py, i = tx * 4 + px;
        feat[(size_t)b * 256 + j * 16 + i] = s * (1.f / 256.f);
    }
}

// ---------------- MLP head ----------------
__global__ __launch_bounds__(64) void mlp_head(
    const float* __restrict__ feat,
    const float* __restrict__ wl1, const float* __restrict__ bl1,
    const float* __restrict__ wl2, const float* __restrict__ bl2,
    float* __restrict__ out)
{
    const int b = blockIdx.x;
    const int t = threadIdx.x;

    __shared__ float sF[256];
    __shared__ float sE[64];
    __shared__ float sL[8];
    __shared__ float sX[8];

    for (int i = t; i < 256; i += 64) sF[i] = feat[(size_t)b * 256 + i];
    __syncthreads();

    float acc = bl1[t];
    for (int k = 0; k < 256; ++k) acc = fmaf(sF[k], wl1[t * 256 + k], acc);
    sE[t] = acc;
    __syncthreads();

    if (t < 8) {
        float l = bl2[t];
#pragma unroll
        for (int k = 0; k < 64; ++k) l = fmaf(sE[k], wl2[t * 64 + k], l);
        sL[t] = l;
    }
    __syncthreads();

    if (t < 8) {
        float m = sL[0];
#pragma unroll
        for (int k = 1; k < 8; ++k) m = fmaxf(m, sL[k]);
        sX[t] = __expf(sL[t] - m);
    }
    __syncthreads();

    if (t < 8) {
        float sum = 0.f;
#pragma unroll
        for (int k = 0; k < 8; ++k) sum += sX[k];
        out[(size_t)b * 8 + t] = sX[t] / sum;
    }
}

extern "C" void kernel_launch(void* const* d_in, const int* in_sizes, int n_in,
                              void* d_out, int out_size, void* d_ws, size_t ws_size,
                              hipStream_t stream) {
    const float* x   = (const float*)d_in[0];
    const float* w1  = (const float*)d_in[1];
    const float* b1  = (const float*)d_in[2];
    const float* w2  = (const float*)d_in[3];
    const float* b2  = (const float*)d_in[4];
    const float* w3  = (const float*)d_in[5];
    const float* b3  = (const float*)d_in[6];
    const float* wl1 = (const float*)d_in[7];
    const float* bl1 = (const float*)d_in[8];
    const float* wl2 = (const float*)d_in[9];
    const float* bl2 = (const float*)d_in[10];
    float* out  = (float*)d_out;

    const size_t FEAT_B = 256u * 256u * 4u;                 // 262144
    const size_t H_B    = (size_t)256 * 3 * 256 * 256 * 2;  // 100663296
    const size_t TAB_B  = 4096;
    float* feat = (float*)d_ws;

    if (ws_size >= FEAT_B + 2 * H_B + TAB_B) {
        unsigned short* h1 = (unsigned short*)((char*)d_ws + FEAT_B);
        unsigned short* h2 = (unsigned short*)((char*)d_ws + FEAT_B + H_B);
        u32* wtab = (u32*)((char*)d_ws + FEAT_B + 2 * H_B);

        pack_weights<<<1, 128, 0, stream>>>(w1, w2, w3, wtab);
        dim3 g(32, 128);
        conv_mfma<true,  3, false, 0 ><<<g, CT, 0, stream>>>(x,  b1, wtab, h1, nullptr);
        conv_mfma<false, 3, false, 45><<<g, CT, 0, stream>>>(h1, b2, wtab, h2, nullptr);
        conv_mfma<false, 1, true,  90><<<g, CT, 0, stream>>>(h2, b3, wtab, nullptr, feat);
    } else {
        dim3 g1(32, 256);
        fused_conv_feat<<<g1, NTHREADS, 0, stream>>>(x, w1, b1, w2, b2, w3, b3, feat);
    }
    mlp_head<<<256, 64, 0, stream>>>(feat, wl1, bl1, wl2, bl2, out);
}

// Round 13
// 285.186 us; speedup vs baseline: 1.7952x; 1.1390x over previous
//
#include <hip/hip_runtime.h>
#include <hip/hip_bf16.h>

// Round 13: FULLY FUSED MFMA conv stack (no HBM intermediates).
//  Per block: one (image, 64x32 tile). Stage x (44 rows x 76 cols x 3ch, bf16)
//  -> conv1 (Toeplitz MFMA, 5cx x rb{0,16,24}, mask OOB->0) -> sH1(40x72x3)
//  -> conv2 (5cx x rb{0,16,20}) -> sH2(36x68x3, aliases sX)
//  -> conv3 (4cx x rb{0,16}) + 16x16 patch means -> feat.
//  Toeplitz math / fragment layouts / perm selectors identical to rounds
//  10-12 (passed, absmax 4.9e-4). Stride 88 ushorts (176B): 2-way banks=free.
//  Duplicate-row chunks write identical values (benign). All out-of-band
//  reads (k in [20,32) zero-weight band, col overhang) land on staged-finite
//  or zeroed-pad LDS -> 0 x finite = 0, no NaN.

#define CT 256

typedef unsigned int u32;
typedef short bf16x8 __attribute__((ext_vector_type(8)));
typedef float f32x4 __attribute__((ext_vector_type(4)));
typedef unsigned int u32x4 __attribute__((ext_vector_type(4)));

static __device__ __forceinline__ unsigned short f2bf(float f) {
    __hip_bfloat16 h = __float2bfloat16(f);
    return *reinterpret_cast<unsigned short*>(&h);
}

#define LS   88
#define XCS  (44 * LS)   // 3872
#define H1CS (40 * LS)   // 3520
#define H2CS (36 * LS)   // 3168
// lds_u layout (ushort idx): sH1 [0,10560) | pad16 | sX [10576,22192) | pad16
#define SH1_OFF 0
#define SX_OFF  10576
#define LDS_U   22208

// ---------------- weight pack ----------------
// tab[t*3+{0,1,2}] = {bf16(w0)|bf16(w1)<<16, bf16(w2)|bf16(w3)<<16, bf16(w4)}
// t: conv1 0..44 ((oc*3+ic)*5+ky), conv2 45..89, conv3 90..104.
__global__ __launch_bounds__(128) void pack_weights(
    const float* __restrict__ w1, const float* __restrict__ w2,
    const float* __restrict__ w3, u32* __restrict__ tab)
{
    const int t = threadIdx.x;
    if (t < 105) {
        const float* w;
        if (t < 45)       w = w1 + t * 5;
        else if (t < 90)  w = w2 + (t - 45) * 5;
        else              w = w3 + (t - 90) * 5;
        tab[t * 3 + 0] = (u32)f2bf(w[0]) | ((u32)f2bf(w[1]) << 16);
        tab[t * 3 + 1] = (u32)f2bf(w[2]) | ((u32)f2bf(w[3]) << 16);
        tab[t * 3 + 2] = (u32)f2bf(w[4]);
    }
}

// ---------------- one fused conv stage (3 oc), LDS -> LDS ----------------
template<int TOFF, int INCS, int OUTCS, int RB2>
static __device__ __forceinline__ void conv_stage_mfma(
    const unsigned short* __restrict__ sin, unsigned short* __restrict__ sout,
    const u32* __restrict__ tab, const float* __restrict__ bias,
    int gy0m, int gx0m, int lanem, int g, int wid,
    const u32* selA, const u32* selB)
{
    f32x4 acc[4][3];
    int rbv[4], cxv[4], baseb[4];
    bool val[4];
#pragma unroll
    for (int i = 0; i < 4; ++i) {
        const int t = wid + 4 * i;
        val[i] = (t < 15);
        const int tc = val[i] ? t : 0;
        cxv[i] = tc % 5;
        const int rbi = tc / 5;
        rbv[i] = (rbi == 0) ? 0 : (rbi == 1 ? 16 : RB2);
        baseb[i] = ((rbv[i] + lanem) * LS + 16 * cxv[i] + g * 8) * 2;
    }
#pragma unroll
    for (int oc = 0; oc < 3; ++oc) {
        const float bb = bias[oc];
#pragma unroll
        for (int i = 0; i < 4; ++i) acc[i][oc] = f32x4{bb, bb, bb, bb};
    }

#pragma unroll
    for (int f = 0; f < 15; ++f) {         // f = ic*5 + ky
        const int ic = f / 5, ky = f % 5;
        bf16x8 A[3];
#pragma unroll
        for (int oc = 0; oc < 3; ++oc) {
            const u32* wt = tab + (TOFF + (oc * 3 + ic) * 5 + ky) * 3;
            const u32 w01 = wt[0], w23 = wt[1], w4z = wt[2];
            u32x4 qv;
#pragma unroll
            for (int jj = 0; jj < 4; ++jj)
                qv[jj] = __builtin_amdgcn_perm(
                    __builtin_amdgcn_perm(w23, w01, selA[jj]), w4z, selB[jj]);
            A[oc] = __builtin_bit_cast(bf16x8, qv);
        }
        const int foff = (ic * INCS + ky * LS) * 2;
#pragma unroll
        for (int i = 0; i < 4; ++i) {
            if (val[i]) {
                const bf16x8 B = *reinterpret_cast<const bf16x8*>(
                    (const char*)sin + baseb[i] + foff);
#pragma unroll
                for (int oc = 0; oc < 3; ++oc)
                    acc[i][oc] = __builtin_amdgcn_mfma_f32_16x16x32_bf16(
                        A[oc], B, acc[i][oc], 0, 0, 0);
            }
        }
    }

    // epilogue: masked ReLU -> bf16 -> LDS
#pragma unroll
    for (int i = 0; i < 4; ++i) {
        if (!val[i]) continue;
        const int Y = gy0m + rbv[i] + lanem;
        const bool yok = (unsigned)Y < 256u;
        const int Xb = gx0m + 16 * cxv[i] + g * 4;
#pragma unroll
        for (int oc = 0; oc < 3; ++oc) {
            float v[4];
#pragma unroll
            for (int p = 0; p < 4; ++p) {
                const bool ok = yok & ((unsigned)(Xb + p) < 256u);
                v[p] = ok ? fmaxf(acc[i][oc][p], 0.f) : 0.f;
            }
            const u32 lo = (u32)f2bf(v[0]) | ((u32)f2bf(v[1]) << 16);
            const u32 hi = (u32)f2bf(v[2]) | ((u32)f2bf(v[3]) << 16);
            *reinterpret_cast<uint2*>(
                sout + oc * OUTCS + (rbv[i] + lanem) * LS + 16 * cxv[i] + g * 4) =
                make_uint2(lo, hi);
        }
    }
}

// ---------------- fused kernel ----------------
__global__ __launch_bounds__(CT) void fused_mfma(
    const float* __restrict__ x,
    const float* __restrict__ b1, const float* __restrict__ b2,
    const float* __restrict__ b3,
    const u32* __restrict__ tab, float* __restrict__ feat)
{
    const int pos = blockIdx.x;            // 0..31
    const int b   = blockIdx.y;            // image
    const int tx = pos & 3, ty = pos >> 2;
    const int tid = threadIdx.x;
    const int lane = tid & 63, wid = tid >> 6;
    const int lanem = lane & 15, g = lane >> 4;

    __shared__ __align__(16) unsigned short lds_u[LDS_U];   // 44416 B
    unsigned short* sH1 = lds_u + SH1_OFF;
    unsigned short* sX  = lds_u + SX_OFF;
    unsigned short* sH2 = sX;               // alias (conv2 out after sX dead)

    const int gy0 = ty * 32, gx0 = tx * 64;

    // ---- perm selectors (rounds 10-12 verified) ----
    u32 selA[4], selB[4];
#pragma unroll
    for (int jj = 0; jj < 4; ++jj) {
        u32 a = 0, bs = 0;
#pragma unroll
        for (int byt = 0; byt < 4; ++byt) {
            const int j = 2 * jj + (byt >> 1);
            const int d = g * 8 + j - lanem;
            const int h = byt & 1;
            u32 av, bv;
            if      (d == 0) av = 0 + h;
            else if (d == 1) av = 2 + h;
            else if (d == 2) av = 4 + h;
            else if (d == 3) av = 6 + h;
            else             av = 0;
            if      (d == 4)           bv = 0 + h;   // w4
            else if (d >= 0 && d < 4)  bv = 4 + byt; // keep t1 byte
            else                       bv = 2 + h;   // zero
            a  |= av << (8 * byt);
            bs |= bv << (8 * byt);
        }
        selA[jj] = a; selB[jj] = bs;
    }

    // ---- zero both 16-ushort pads (read by zero-band overhang only) ----
    if (tid < 16) {
        u32* w32 = reinterpret_cast<u32*>(lds_u);
        if (tid < 8) w32[(SX_OFF + 3 * XCS) / 2 + tid] = 0;       // sX pad
        else         w32[(SH1_OFF + 3 * H1CS) / 2 + (tid - 8)] = 0; // sH1 pad
    }

    // ---- stage x: 44 rows x 88 cols (76 data + 12 zero) x 3 ch, bf16 ----
    for (int p = tid; p < 44 * 44; p += CT) {
        const int r = p / 44;
        const int k = p - r * 44;
        const int gy = gy0 - 6 + r;
        const int gx = gx0 - 6 + 2 * k;
        const bool yok  = ((unsigned)gy < 256u) & (k < 38);
        const bool full = yok & (gx >= 0) & (gx + 1 < 256);
#pragma unroll
        for (int c = 0; c < 3; ++c) {
            u32 packed = 0;
            if (yok) {
                const float* src = x + (((size_t)b * 3 + c) * 256 + gy) * 256;
                float vx = 0.f, vy = 0.f;
                if (full) {
                    const float2 v = *reinterpret_cast<const float2*>(src + gx);
                    vx = v.x; vy = v.y;
                } else {
                    if ((unsigned)gx < 256u)       vx = src[gx];
                    if ((unsigned)(gx + 1) < 256u) vy = src[gx + 1];
                }
                packed = (u32)f2bf(vx) | ((u32)f2bf(vy) << 16);
            }
            *reinterpret_cast<u32*>(&sX[c * XCS + r * LS + 2 * k]) = packed;
        }
    }
    __syncthreads();

    // ---- conv1: sX -> sH1 (40 rows x 72 cols x 3), origin (gy0-4, gx0-4) ----
    conv_stage_mfma<0, XCS, H1CS, 24>(sX, sH1, tab, b1,
                                      gy0 - 4, gx0 - 4, lanem, g, wid, selA, selB);
    __syncthreads();

    // ---- conv2: sH1 -> sH2 (36 x 68 x 3), origin (gy0-2, gx0-2) ----
    conv_stage_mfma<45, H1CS, H2CS, 20>(sH1, sH2, tab, b2,
                                        gy0 - 2, gx0 - 2, lanem, g, wid, selA, selB);
    __syncthreads();

    // ---- conv3 + patch-mean: sH2 -> feat; tiles (cx=wid, rb in {0,16}) ----
    {
        const float bb = b3[0];
        f32x4 a3[2] = {f32x4{bb, bb, bb, bb}, f32x4{bb, bb, bb, bb}};
        int base_s[2];
#pragma unroll
        for (int s = 0; s < 2; ++s)
            base_s[s] = ((s * 16 + lanem) * LS + 16 * wid + g * 8) * 2;

#pragma unroll
        for (int f = 0; f < 15; ++f) {
            const int ic = f / 5, ky = f % 5;
            const u32* wt = tab + (90 + f) * 3;
            const u32 w01 = wt[0], w23 = wt[1], w4z = wt[2];
            u32x4 qv;
#pragma unroll
            for (int jj = 0; jj < 4; ++jj)
                qv[jj] = __builtin_amdgcn_perm(
                    __builtin_amdgcn_perm(w23, w01, selA[jj]), w4z, selB[jj]);
            const bf16x8 A = __builtin_bit_cast(bf16x8, qv);
            const int foff = (ic * H2CS + ky * LS) * 2;
#pragma unroll
            for (int s = 0; s < 2; ++s) {
                const bf16x8 B = *reinterpret_cast<const bf16x8*>(
                    (const char*)sH2 + base_s[s] + foff);
                a3[s] = __builtin_amdgcn_mfma_f32_16x16x32_bf16(A, B, a3[s], 0, 0, 0);
            }
        }
#pragma unroll
        for (int s = 0; s < 2; ++s) {
            float sum = fmaxf(a3[s][0], 0.f) + fmaxf(a3[s][1], 0.f)
                      + fmaxf(a3[s][2], 0.f) + fmaxf(a3[s][3], 0.f);
            sum += __shfl_xor(sum, 1, 64);
            sum += __shfl_xor(sum, 2, 64);
            sum += __shfl_xor(sum, 4, 64);
            sum += __shfl_xor(sum, 8, 64);
            sum += __shfl_xor(sum, 16, 64);
            sum += __shfl_xor(sum, 32, 64);
            if (lane == 0) {
                const int j = ty * 2 + s, i2 = tx * 4 + wid;
                feat[(size_t)b * 256 + j * 16 + i2] = sum * (1.f / 256.f);
            }
        }
    }
}

// ---------------- MLP head ----------------
__global__ __launch_bounds__(64) void mlp_head(
    const float* __restrict__ feat,
    const float* __restrict__ wl1, const float* __restrict__ bl1,
    const float* __restrict__ wl2, const float* __restrict__ bl2,
    float* __restrict__ out)
{
    const int b = blockIdx.x;
    const int t = threadIdx.x;

    __shared__ float sF[256];
    __shared__ float sE[64];
    __shared__ float sL[8];
    __shared__ float sXx[8];

    for (int i = t; i < 256; i += 64) sF[i] = feat[(size_t)b * 256 + i];
    __syncthreads();

    float acc = bl1[t];
    for (int k = 0; k < 256; ++k) acc = fmaf(sF[k], wl1[t * 256 + k], acc);
    sE[t] = acc;
    __syncthreads();

    if (t < 8) {
        float l = bl2[t];
#pragma unroll
        for (int k = 0; k < 64; ++k) l = fmaf(sE[k], wl2[t * 64 + k], l);
        sL[t] = l;
    }
    __syncthreads();

    if (t < 8) {
        float m = sL[0];
#pragma unroll
        for (int k = 1; k < 8; ++k) m = fmaxf(m, sL[k]);
        sXx[t] = __expf(sL[t] - m);
    }
    __syncthreads();

    if (t < 8) {
        float sum = 0.f;
#pragma unroll
        for (int k = 0; k < 8; ++k) sum += sXx[k];
        out[(size_t)b * 8 + t] = sXx[t] / sum;
    }
}

// ---------------- scalar fused fallback (round-3) ----------------
#define NTHREADS 512

template<int ICn, int OCn, int OW, int OH, int IS, int ICSZ, int OS, int OCSZ, bool MASK>
__device__ __forceinline__ void conv5x5(
    const float* __restrict__ sin, float* __restrict__ sout,
    const float* __restrict__ w, const float* __restrict__ bias,
    int gy0, int gx0, int tid)
{
    constexpr int QX = OW / 4;
    constexpr int RY = OH / 2;
    constexpr int TASKS = QX * RY;
    if (tid < TASKS) {
        const int ry = tid / QX;
        const int qx = tid - ry * QX;
        const int y0 = ry * 2, x0 = qx * 4;
        float acc[2][OCn][4];
#pragma unroll
        for (int c = 0; c < OCn; ++c) {
            const float bb = bias[c];
#pragma unroll
            for (int p = 0; p < 4; ++p) { acc[0][c][p] = bb; acc[1][c][p] = bb; }
        }
#pragma unroll
        for (int ic = 0; ic < ICn; ++ic) {
            const float* base = sin + ic * ICSZ + y0 * IS + x0;
#pragma unroll
            for (int r = 0; r < 6; ++r) {
                const float4 a4 = *reinterpret_cast<const float4*>(base + r * IS);
                const float4 b4 = *reinterpret_cast<const float4*>(base + r * IS + 4);
                const float v[8] = {a4.x, a4.y, a4.z, a4.w, b4.x, b4.y, b4.z, b4.w};
#pragma unroll
                for (int kx = 0; kx < 5; ++kx)
#pragma unroll
                    for (int c = 0; c < OCn; ++c) {
                        if (r < 5) {
                            const float wv = w[((c * ICn + ic) * 5 + r) * 5 + kx];
#pragma unroll
                            for (int p = 0; p < 4; ++p)
                                acc[0][c][p] = fmaf(v[p + kx], wv, acc[0][c][p]);
                        }
                        if (r >= 1) {
                            const float wv = w[((c * ICn + ic) * 5 + (r - 1)) * 5 + kx];
#pragma unroll
                            for (int p = 0; p < 4; ++p)
                                acc[1][c][p] = fmaf(v[p + kx], wv, acc[1][c][p]);
                        }
                    }
            }
        }
#pragma unroll
        for (int rr = 0; rr < 2; ++rr) {
            const int gy = gy0 + y0 + rr;
#pragma unroll
            for (int c = 0; c < OCn; ++c) {
                float o[4];
#pragma unroll
                for (int p = 0; p < 4; ++p) {
                    float rv = fmaxf(acc[rr][c][p], 0.f);
                    if (MASK) {
                        const int gx = gx0 + x0 + p;
                        const bool ok = ((unsigned)gy < 256u) & ((unsigned)gx < 256u);
                        rv = ok ? rv : 0.f;
                    }
                    o[p] = rv;
                }
                *reinterpret_cast<float4*>(&sout[c * OCSZ + (y0 + rr) * OS + x0]) =
                    make_float4(o[0], o[1], o[2], o[3]);
            }
        }
    }
}

__global__ __launch_bounds__(NTHREADS) void fused_conv_feat(
    const float* __restrict__ x,
    const float* __restrict__ w1, const float* __restrict__ b1,
    const float* __restrict__ w2, const float* __restrict__ b2,
    const float* __restrict__ w3, const float* __restrict__ b3,
    float* __restrict__ feat)
{
    const int tile = blockIdx.x;
    const int b    = blockIdx.y;
    const int tx   = tile & 3, ty = tile >> 2;
    const int tid  = threadIdx.x;

    __shared__ __align__(16) float lds[10032 + 9120];
    float* sIn = lds;
    float* sH1 = lds + 10032;
    float* sH2 = lds;
    float* sH3 = lds + 10032;

    const int gy0s = ty * 32 - 6, gx0s = tx * 64 - 6;
    for (int i = tid; i < 3 * 44 * 38; i += NTHREADS) {
        const int c   = i / 1672;
        const int rem = i - c * 1672;
        const int r   = rem / 38;
        const int k   = rem - r * 38;
        const int gy = gy0s + r, gx = gx0s + 2 * k;
        float2 v = make_float2(0.f, 0.f);
        if ((unsigned)gy < 256u) {
            const float* src = x + (((size_t)b * 3 + c) * 256 + gy) * 256;
            if (gx >= 0 && gx + 1 < 256) {
                v = *reinterpret_cast<const float2*>(src + gx);
            } else {
                if ((unsigned)gx < 256u)       v.x = src[gx];
                if ((unsigned)(gx + 1) < 256u) v.y = src[gx + 1];
            }
        }
        *reinterpret_cast<float2*>(&sIn[c * 3344 + r * 76 + 2 * k]) = v;
    }
    __syncthreads();

    conv5x5<3, 3, 72, 40, 76, 3344, 76, 3040, true>(sIn, sH1, w1, b1,
                                                    ty * 32 - 4, tx * 64 - 4, tid);
    __syncthreads();
    conv5x5<3, 3, 68, 36, 76, 3040, 76, 2736, true>(sH1, sH2, w2, b2,
                                                    ty * 32 - 2, tx * 64 - 2, tid);
    __syncthreads();
    conv5x5<3, 1, 64, 32, 76, 2736, 64, 2048, false>(sH2, sH3, w3, b3, 0, 0, tid);
    __syncthreads();

    const int wv   = tid >> 6;
    const int lane = tid & 63;
    const int py = wv >> 2, px = wv & 3;
    float s = 0.f;
#pragma unroll
    for (int k = 0; k < 4; ++k) {
        const int idx = lane + k * 64;
        const int r = idx >> 4, cc = idx & 15;
        s += sH3[(py * 16 + r) * 64 + px * 16 + cc];
    }
#pragma unroll
    for (int off = 32; off > 0; off >>= 1) s += __shfl_down(s, off, 64);
    if (lane == 0) {
        const int j = ty * 2 + py, i = tx * 4 + px;
        feat[(size_t)b * 256 + j * 16 + i] = s * (1.f / 256.f);
    }
}

extern "C" void kernel_launch(void* const* d_in, const int* in_sizes, int n_in,
                              void* d_out, int out_size, void* d_ws, size_t ws_size,
                              hipStream_t stream) {
    const float* x   = (const float*)d_in[0];
    const float* w1  = (const float*)d_in[1];
    const float* b1  = (const float*)d_in[2];
    const float* w2  = (const float*)d_in[3];
    const float* b2  = (const float*)d_in[4];
    const float* w3  = (const float*)d_in[5];
    const float* b3  = (const float*)d_in[6];
    const float* wl1 = (const float*)d_in[7];
    const float* bl1 = (const float*)d_in[8];
    const float* wl2 = (const float*)d_in[9];
    const float* bl2 = (const float*)d_in[10];
    float* out  = (float*)d_out;

    const size_t FEAT_B = 256u * 256u * 4u;   // 262144
    const size_t TAB_B  = 4096;
    float* feat = (float*)d_ws;

    if (ws_size >= FEAT_B + TAB_B) {
        u32* wtab = (u32*)((char*)d_ws + FEAT_B);
        pack_weights<<<1, 128, 0, stream>>>(w1, w2, w3, wtab);
        dim3 g(32, 256);
        fused_mfma<<<g, CT, 0, stream>>>(x, b1, b2, b3, wtab, feat);
    } else {
        dim3 g1(32, 256);
        fused_conv_feat<<<g1, NTHREADS, 0, stream>>>(x, w1, b1, w2, b2, w3, b3, feat);
    }
    mlp_head<<<256, 64, 0, stream>>>(feat, wl1, bl1, wl2, bl2, out);
}

// Round 14
// 242.304 us; speedup vs baseline: 2.1129x; 1.1770x over previous
//
#include <hip/hip_runtime.h>
#include <hip/hip_bf16.h>

// Round 14: fused MFMA conv stack, LDS diet -> 4 blocks/CU.
//  Changes vs round 13 (285us, passed):
//  - sH1/sH2 row stride 72 ushorts (144B: 16B-aligned, start banks 4r%32 ->
//    2 rows/bank = conflict-free). sX keeps stride 88. LDS 44.4 -> 39.6 KB
//    => 4 blocks/CU (occupancy 33.7 -> ~44%).
//  - Stores with tile col-base >= 72 skipped (would wrap into next row;
//    analysis: only discardable lanes). Duplicate-row stores removed
//    (rb2 tile stores lanem >= 32-RB2 only) -> no same-address write races.
//  - Interior blocks (tx in {1,2}, ty in {1..6}): predicate-free staging
//    (stage all 88 cols as real data -- only zero-band reads touch >75)
//    and unmasked epilogues.
//  Math bit-identical to rounds 10-13 (absmax 4.9e-4).

#define CT 256

typedef unsigned int u32;
typedef short bf16x8 __attribute__((ext_vector_type(8)));
typedef float f32x4 __attribute__((ext_vector_type(4)));
typedef unsigned int u32x4 __attribute__((ext_vector_type(4)));

static __device__ __forceinline__ unsigned short f2bf(float f) {
    __hip_bfloat16 h = __float2bfloat16(f);
    return *reinterpret_cast<unsigned short*>(&h);
}

#define LSX   88
#define XCS   (44 * LSX)          // 3872
#define LS1   72
#define H1CS  (40 * LS1)          // 2880
#define H2CS  (36 * LS1)          // 2592
// ushort layout: sH1 [0,8640) | pad24 | sX [8664,20280) | pad16
#define SH1_OFF 0
#define SX_OFF  (3 * H1CS + 24)   // 8664 (x2B = 17328, 16B-aligned)
#define LDS_U   20296             // 40592 B -> 4 blocks/CU

// ---------------- weight pack ----------------
// tab[t*3+{0,1,2}] = {bf16(w0)|bf16(w1)<<16, bf16(w2)|bf16(w3)<<16, bf16(w4)}
// t: conv1 0..44 ((oc*3+ic)*5+ky), conv2 45..89, conv3 90..104.
__global__ __launch_bounds__(128) void pack_weights(
    const float* __restrict__ w1, const float* __restrict__ w2,
    const float* __restrict__ w3, u32* __restrict__ tab)
{
    const int t = threadIdx.x;
    if (t < 105) {
        const float* w;
        if (t < 45)       w = w1 + t * 5;
        else if (t < 90)  w = w2 + (t - 45) * 5;
        else              w = w3 + (t - 90) * 5;
        tab[t * 3 + 0] = (u32)f2bf(w[0]) | ((u32)f2bf(w[1]) << 16);
        tab[t * 3 + 1] = (u32)f2bf(w[2]) | ((u32)f2bf(w[3]) << 16);
        tab[t * 3 + 2] = (u32)f2bf(w[4]);
    }
}

// ---------------- one fused conv stage (3 oc), LDS -> LDS ----------------
template<int TOFF, int LSI, int INCS, int LSO, int OUTCS, int RB2>
static __device__ __forceinline__ void conv_stage_mfma(
    const unsigned short* __restrict__ sin, unsigned short* __restrict__ sout,
    const u32* __restrict__ tab, const float* __restrict__ bias,
    int gy0m, int gx0m, int lanem, int g, int wid,
    const u32* selA, const u32* selB, bool interior)
{
    f32x4 acc[4][3];
    int rbv[4], cxv[4], rbi[4], baseb[4];
    bool val[4];
#pragma unroll
    for (int i = 0; i < 4; ++i) {
        const int t = wid + 4 * i;
        val[i] = (t < 15);
        const int tc = val[i] ? t : 0;
        cxv[i] = tc % 5;
        rbi[i] = tc / 5;
        rbv[i] = (rbi[i] == 0) ? 0 : (rbi[i] == 1 ? 16 : RB2);
        baseb[i] = ((rbv[i] + lanem) * LSI + 16 * cxv[i] + g * 8) * 2;
    }
#pragma unroll
    for (int oc = 0; oc < 3; ++oc) {
        const float bb = bias[oc];
#pragma unroll
        for (int i = 0; i < 4; ++i) acc[i][oc] = f32x4{bb, bb, bb, bb};
    }

#pragma unroll
    for (int f = 0; f < 15; ++f) {         // f = ic*5 + ky
        const int ic = f / 5, ky = f % 5;
        bf16x8 A[3];
#pragma unroll
        for (int oc = 0; oc < 3; ++oc) {
            const u32* wt = tab + (TOFF + (oc * 3 + ic) * 5 + ky) * 3;
            const u32 w01 = wt[0], w23 = wt[1], w4z = wt[2];
            u32x4 qv;
#pragma unroll
            for (int jj = 0; jj < 4; ++jj)
                qv[jj] = __builtin_amdgcn_perm(
                    __builtin_amdgcn_perm(w23, w01, selA[jj]), w4z, selB[jj]);
            A[oc] = __builtin_bit_cast(bf16x8, qv);
        }
        const int foff = (ic * INCS + ky * LSI) * 2;
#pragma unroll
        for (int i = 0; i < 4; ++i) {
            if (val[i]) {
                const bf16x8 B = *reinterpret_cast<const bf16x8*>(
                    (const char*)sin + baseb[i] + foff);
#pragma unroll
                for (int oc = 0; oc < 3; ++oc)
                    acc[i][oc] = __builtin_amdgcn_mfma_f32_16x16x32_bf16(
                        A[oc], B, acc[i][oc], 0, 0, 0);
            }
        }
    }

    // epilogue: ReLU (+mask if boundary) -> bf16 -> LDS
#pragma unroll
    for (int i = 0; i < 4; ++i) {
        if (!val[i]) continue;
        const int colbase = 16 * cxv[i] + 4 * g;
        if (colbase >= LSO) continue;                    // stride-72 overflow
        if (rbi[i] == 2 && lanem < 32 - RB2) continue;   // duplicate rows
        const int row = rbv[i] + lanem;
        const int Y = gy0m + row;
        const bool yok = (unsigned)Y < 256u;
#pragma unroll
        for (int oc = 0; oc < 3; ++oc) {
            float v[4];
#pragma unroll
            for (int p = 0; p < 4; ++p) {
                float rv = fmaxf(acc[i][oc][p], 0.f);
                if (!interior) {
                    const bool ok = yok & ((unsigned)(gx0m + colbase + p) < 256u);
                    rv = ok ? rv : 0.f;
                }
                v[p] = rv;
            }
            const u32 lo = (u32)f2bf(v[0]) | ((u32)f2bf(v[1]) << 16);
            const u32 hi = (u32)f2bf(v[2]) | ((u32)f2bf(v[3]) << 16);
            *reinterpret_cast<uint2*>(
                sout + oc * OUTCS + row * LSO + colbase) = make_uint2(lo, hi);
        }
    }
}

// ---------------- fused kernel ----------------
__global__ __launch_bounds__(CT) void fused_mfma(
    const float* __restrict__ x,
    const float* __restrict__ b1, const float* __restrict__ b2,
    const float* __restrict__ b3,
    const u32* __restrict__ tab, float* __restrict__ feat)
{
    const int pos = blockIdx.x;            // 0..31
    const int b   = blockIdx.y;            // image
    const int tx = pos & 3, ty = pos >> 2;
    const int tid = threadIdx.x;
    const int lane = tid & 63, wid = tid >> 6;
    const int lanem = lane & 15, g = lane >> 4;

    __shared__ __align__(16) unsigned short lds_u[LDS_U];   // 40592 B
    unsigned short* sH1 = lds_u + SH1_OFF;
    unsigned short* sX  = lds_u + SX_OFF;
    unsigned short* sH2 = sX;               // alias (sX dead after conv1)

    const int gy0 = ty * 32, gx0 = tx * 64;
    const bool interior = (tx >= 1) & (tx <= 2) & (ty >= 1) & (ty <= 6);

    // ---- perm selectors (rounds 10-13 verified) ----
    u32 selA[4], selB[4];
#pragma unroll
    for (int jj = 0; jj < 4; ++jj) {
        u32 a = 0, bs = 0;
#pragma unroll
        for (int byt = 0; byt < 4; ++byt) {
            const int j = 2 * jj + (byt >> 1);
            const int d = g * 8 + j - lanem;
            const int h = byt & 1;
            u32 av, bv;
            if      (d == 0) av = 0 + h;
            else if (d == 1) av = 2 + h;
            else if (d == 2) av = 4 + h;
            else if (d == 3) av = 6 + h;
            else             av = 0;
            if      (d == 4)           bv = 0 + h;   // w4
            else if (d >= 0 && d < 4)  bv = 4 + byt; // keep t1 byte
            else                       bv = 2 + h;   // zero
            a  |= av << (8 * byt);
            bs |= bv << (8 * byt);
        }
        selA[jj] = a; selB[jj] = bs;
    }

    // ---- zero the tail pads (only zero-band overflow reads touch them) ----
    {
        u32* w32 = reinterpret_cast<u32*>(lds_u);
        if (tid < 12)                    w32[(3 * H1CS) / 2 + tid] = 0;
        else if (tid < 20)               w32[(SX_OFF + 3 * XCS) / 2 + (tid - 12)] = 0;
    }

    // ---- stage x: 44 rows x 88 cols x 3 ch, bf16 ----
    if (interior) {
        for (int p = tid; p < 44 * 44; p += CT) {
            const int r = p / 44;
            const int k = p - r * 44;
            const int gy = gy0 - 6 + r;
            const int gx = gx0 - 6 + 2 * k;
#pragma unroll
            for (int c = 0; c < 3; ++c) {
                const float2 v = *reinterpret_cast<const float2*>(
                    x + (((size_t)b * 3 + c) * 256 + gy) * 256 + gx);
                const u32 packed = (u32)f2bf(v.x) | ((u32)f2bf(v.y) << 16);
                *reinterpret_cast<u32*>(&sX[c * XCS + r * LSX + 2 * k]) = packed;
            }
        }
    } else {
        for (int p = tid; p < 44 * 44; p += CT) {
            const int r = p / 44;
            const int k = p - r * 44;
            const int gy = gy0 - 6 + r;
            const int gx = gx0 - 6 + 2 * k;
            const bool yok  = ((unsigned)gy < 256u) & (k < 38);
            const bool full = yok & (gx >= 0) & (gx + 1 < 256);
#pragma unroll
            for (int c = 0; c < 3; ++c) {
                u32 packed = 0;
                if (yok) {
                    const float* src = x + (((size_t)b * 3 + c) * 256 + gy) * 256;
                    float vx = 0.f, vy = 0.f;
                    if (full) {
                        const float2 v = *reinterpret_cast<const float2*>(src + gx);
                        vx = v.x; vy = v.y;
                    } else {
                        if ((unsigned)gx < 256u)       vx = src[gx];
                        if ((unsigned)(gx + 1) < 256u) vy = src[gx + 1];
                    }
                    packed = (u32)f2bf(vx) | ((u32)f2bf(vy) << 16);
                }
                *reinterpret_cast<u32*>(&sX[c * XCS + r * LSX + 2 * k]) = packed;
            }
        }
    }
    __syncthreads();

    // ---- conv1: sX(88) -> sH1(72), origin (gy0-4, gx0-4) ----
    conv_stage_mfma<0, LSX, XCS, LS1, H1CS, 24>(sX, sH1, tab, b1,
        gy0 - 4, gx0 - 4, lanem, g, wid, selA, selB, interior);
    __syncthreads();

    // ---- conv2: sH1(72) -> sH2(72), origin (gy0-2, gx0-2) ----
    conv_stage_mfma<45, LS1, H1CS, LS1, H2CS, 20>(sH1, sH2, tab, b2,
        gy0 - 2, gx0 - 2, lanem, g, wid, selA, selB, interior);
    __syncthreads();

    // ---- conv3 + patch-mean: sH2 -> feat; tiles (cx=wid, rb in {0,16}) ----
    {
        const float bb = b3[0];
        f32x4 a3[2] = {f32x4{bb, bb, bb, bb}, f32x4{bb, bb, bb, bb}};
        int base_s[2];
#pragma unroll
        for (int s = 0; s < 2; ++s)
            base_s[s] = ((s * 16 + lanem) * LS1 + 16 * wid + g * 8) * 2;

#pragma unroll
        for (int f = 0; f < 15; ++f) {
            const int ic = f / 5, ky = f % 5;
            const u32* wt = tab + (90 + f) * 3;
            const u32 w01 = wt[0], w23 = wt[1], w4z = wt[2];
            u32x4 qv;
#pragma unroll
            for (int jj = 0; jj < 4; ++jj)
                qv[jj] = __builtin_amdgcn_perm(
                    __builtin_amdgcn_perm(w23, w01, selA[jj]), w4z, selB[jj]);
            const bf16x8 A = __builtin_bit_cast(bf16x8, qv);
            const int foff = (ic * H2CS + ky * LS1) * 2;
#pragma unroll
            for (int s = 0; s < 2; ++s) {
                const bf16x8 B = *reinterpret_cast<const bf16x8*>(
                    (const char*)sH2 + base_s[s] + foff);
                a3[s] = __builtin_amdgcn_mfma_f32_16x16x32_bf16(A, B, a3[s], 0, 0, 0);
            }
        }
#pragma unroll
        for (int s = 0; s < 2; ++s) {
            float sum = fmaxf(a3[s][0], 0.f) + fmaxf(a3[s][1], 0.f)
                      + fmaxf(a3[s][2], 0.f) + fmaxf(a3[s][3], 0.f);
            sum += __shfl_xor(sum, 1, 64);
            sum += __shfl_xor(sum, 2, 64);
            sum += __shfl_xor(sum, 4, 64);
            sum += __shfl_xor(sum, 8, 64);
            sum += __shfl_xor(sum, 16, 64);
            sum += __shfl_xor(sum, 32, 64);
            if (lane == 0) {
                const int j = ty * 2 + s, i2 = tx * 4 + wid;
                feat[(size_t)b * 256 + j * 16 + i2] = sum * (1.f / 256.f);
            }
        }
    }
}

// ---------------- MLP head ----------------
__global__ __launch_bounds__(64) void mlp_head(
    const float* __restrict__ feat,
    const float* __restrict__ wl1, const float* __restrict__ bl1,
    const float* __restrict__ wl2, const float* __restrict__ bl2,
    float* __restrict__ out)
{
    const int b = blockIdx.x;
    const int t = threadIdx.x;

    __shared__ float sF[256];
    __shared__ float sE[64];
    __shared__ float sL[8];
    __shared__ float sXx[8];

    for (int i = t; i < 256; i += 64) sF[i] = feat[(size_t)b * 256 + i];
    __syncthreads();

    float acc = bl1[t];
    for (int k = 0; k < 256; ++k) acc = fmaf(sF[k], wl1[t * 256 + k], acc);
    sE[t] = acc;
    __syncthreads();

    if (t < 8) {
        float l = bl2[t];
#pragma unroll
        for (int k = 0; k < 64; ++k) l = fmaf(sE[k], wl2[t * 64 + k], l);
        sL[t] = l;
    }
    __syncthreads();

    if (t < 8) {
        float m = sL[0];
#pragma unroll
        for (int k = 1; k < 8; ++k) m = fmaxf(m, sL[k]);
        sXx[t] = __expf(sL[t] - m);
    }
    __syncthreads();

    if (t < 8) {
        float sum = 0.f;
#pragma unroll
        for (int k = 0; k < 8; ++k) sum += sXx[k];
        out[(size_t)b * 8 + t] = sXx[t] / sum;
    }
}

// ---------------- scalar fused fallback (round-3) ----------------
#define NTHREADS 512

template<int ICn, int OCn, int OW, int OH, int IS, int ICSZ, int OS, int OCSZ, bool MASK>
__device__ __forceinline__ void conv5x5(
    const float* __restrict__ sin, float* __restrict__ sout,
    const float* __restrict__ w, const float* __restrict__ bias,
    int gy0, int gx0, int tid)
{
    constexpr int QX = OW / 4;
    constexpr int RY = OH / 2;
    constexpr int TASKS = QX * RY;
    if (tid < TASKS) {
        const int ry = tid / QX;
        const int qx = tid - ry * QX;
        const int y0 = ry * 2, x0 = qx * 4;
        float acc[2][OCn][4];
#pragma unroll
        for (int c = 0; c < OCn; ++c) {
            const float bb = bias[c];
#pragma unroll
            for (int p = 0; p < 4; ++p) { acc[0][c][p] = bb; acc[1][c][p] = bb; }
        }
#pragma unroll
        for (int ic = 0; ic < ICn; ++ic) {
            const float* base = sin + ic * ICSZ + y0 * IS + x0;
#pragma unroll
            for (int r = 0; r < 6; ++r) {
                const float4 a4 = *reinterpret_cast<const float4*>(base + r * IS);
                const float4 b4 = *reinterpret_cast<const float4*>(base + r * IS + 4);
                const float v[8] = {a4.x, a4.y, a4.z, a4.w, b4.x, b4.y, b4.z, b4.w};
#pragma unroll
                for (int kx = 0; kx < 5; ++kx)
#pragma unroll
                    for (int c = 0; c < OCn; ++c) {
                        if (r < 5) {
                            const float wv = w[((c * ICn + ic) * 5 + r) * 5 + kx];
#pragma unroll
                            for (int p = 0; p < 4; ++p)
                                acc[0][c][p] = fmaf(v[p + kx], wv, acc[0][c][p]);
                        }
                        if (r >= 1) {
                            const float wv = w[((c * ICn + ic) * 5 + (r - 1)) * 5 + kx];
#pragma unroll
                            for (int p = 0; p < 4; ++p)
                                acc[1][c][p] = fmaf(v[p + kx], wv, acc[1][c][p]);
                        }
                    }
            }
        }
#pragma unroll
        for (int rr = 0; rr < 2; ++rr) {
            const int gy = gy0 + y0 + rr;
#pragma unroll
            for (int c = 0; c < OCn; ++c) {
                float o[4];
#pragma unroll
                for (int p = 0; p < 4; ++p) {
                    float rv = fmaxf(acc[rr][c][p], 0.f);
                    if (MASK) {
                        const int gx = gx0 + x0 + p;
                        const bool ok = ((unsigned)gy < 256u) & ((unsigned)gx < 256u);
                        rv = ok ? rv : 0.f;
                    }
                    o[p] = rv;
                }
                *reinterpret_cast<float4*>(&sout[c * OCSZ + (y0 + rr) * OS + x0]) =
                    make_float4(o[0], o[1], o[2], o[3]);
            }
        }
    }
}

__global__ __launch_bounds__(NTHREADS) void fused_conv_feat(
    const float* __restrict__ x,
    const float* __restrict__ w1, const float* __restrict__ b1,
    const float* __restrict__ w2, const float* __restrict__ b2,
    const float* __restrict__ w3, const float* __restrict__ b3,
    float* __restrict__ feat)
{
    const int tile = blockIdx.x;
    const int b    = blockIdx.y;
    const int tx   = tile & 3, ty = tile >> 2;
    const int tid  = threadIdx.x;

    __shared__ __align__(16) float lds[10032 + 9120];
    float* sIn = lds;
    float* sH1 = lds + 10032;
    float* sH2 = lds;
    float* sH3 = lds + 10032;

    const int gy0s = ty * 32 - 6, gx0s = tx * 64 - 6;
    for (int i = tid; i < 3 * 44 * 38; i += NTHREADS) {
        const int c   = i / 1672;
        const int rem = i - c * 1672;
        const int r   = rem / 38;
        const int k   = rem - r * 38;
        const int gy = gy0s + r, gx = gx0s + 2 * k;
        float2 v = make_float2(0.f, 0.f);
        if ((unsigned)gy < 256u) {
            const float* src = x + (((size_t)b * 3 + c) * 256 + gy) * 256;
            if (gx >= 0 && gx + 1 < 256) {
                v = *reinterpret_cast<const float2*>(src + gx);
            } else {
                if ((unsigned)gx < 256u)       v.x = src[gx];
                if ((unsigned)(gx + 1) < 256u) v.y = src[gx + 1];
            }
        }
        *reinterpret_cast<float2*>(&sIn[c * 3344 + r * 76 + 2 * k]) = v;
    }
    __syncthreads();

    conv5x5<3, 3, 72, 40, 76, 3344, 76, 3040, true>(sIn, sH1, w1, b1,
                                                    ty * 32 - 4, tx * 64 - 4, tid);
    __syncthreads();
    conv5x5<3, 3, 68, 36, 76, 3040, 76, 2736, true>(sH1, sH2, w2, b2,
                                                    ty * 32 - 2, tx * 64 - 2, tid);
    __syncthreads();
    conv5x5<3, 1, 64, 32, 76, 2736, 64, 2048, false>(sH2, sH3, w3, b3, 0, 0, tid);
    __syncthreads();

    const int wv   = tid >> 6;
    const int lane = tid & 63;
    const int py = wv >> 2, px = wv & 3;
    float s = 0.f;
#pragma unroll
    for (int k = 0; k < 4; ++k) {
        const int idx = lane + k * 64;
        const int r = idx >> 4, cc = idx & 15;
        s += sH3[(py * 16 + r) * 64 + px * 16 + cc];
    }
#pragma unroll
    for (int off = 32; off > 0; off >>= 1) s += __shfl_down(s, off, 64);
    if (lane == 0) {
        const int j = ty * 2 + py, i = tx * 4 + px;
        feat[(size_t)b * 256 + j * 16 + i] = s * (1.f / 256.f);
    }
}

extern "C" void kernel_launch(void* const* d_in, const int* in_sizes, int n_in,
                              void* d_out, int out_size, void* d_ws, size_t ws_size,
                              hipStream_t stream) {
    const float* x   = (const float*)d_in[0];
    const float* w1  = (const float*)d_in[1];
    const float* b1  = (const float*)d_in[2];
    const float* w2  = (const float*)d_in[3];
    const float* b2  = (const float*)d_in[4];
    const float* w3  = (const float*)d_in[5];
    const float* b3  = (const float*)d_in[6];
    const float* wl1 = (const float*)d_in[7];
    const float* bl1 = (const float*)d_in[8];
    const float* wl2 = (const float*)d_in[9];
    const float* bl2 = (const float*)d_in[10];
    float* out  = (float*)d_out;

    const size_t FEAT_B = 256u * 256u * 4u;   // 262144
    const size_t TAB_B  = 4096;
    float* feat = (float*)d_ws;

    if (ws_size >= FEAT_B + TAB_B) {
        u32* wtab = (u32*)((char*)d_ws + FEAT_B);
        pack_weights<<<1, 128, 0, stream>>>(w1, w2, w3, wtab);
        dim3 g(32, 256);
        fused_mfma<<<g, CT, 0, stream>>>(x, b1, b2, b3, wtab, feat);
    } else {
        dim3 g1(32, 256);
        fused_conv_feat<<<g1, NTHREADS, 0, stream>>>(x, w1, b1, w2, b2, w3, b3, feat);
    }
    mlp_head<<<256, 64, 0, stream>>>(feat, wl1, bl1, wl2, bl2, out);
}